// Round 6
// baseline (392.140 us; speedup 1.0000x reference)
//
#include <hip/hip_runtime.h>

typedef _Float16 half_t;
typedef _Float16 half4 __attribute__((ext_vector_type(4)));
typedef _Float16 half8 __attribute__((ext_vector_type(8)));
typedef float f32x4 __attribute__((ext_vector_type(4)));

#define AS1 __attribute__((address_space(1)))
#define AS3 __attribute__((address_space(3)))

static constexpr int NBATCH = 65536;

// ---------- z f32 -> f16 into act[:,512:640] ----------
__global__ __launch_bounds__(256) void k_cvtz(const float* __restrict__ z,
                                              half_t* __restrict__ dst) {
  size_t i = (size_t)blockIdx.x * 256 + threadIdx.x;
  int row = (int)(i >> 4), c8 = (int)(i & 15) << 3;
  const float* s = z + (size_t)row * 128 + c8;
  float4 v0 = *(const float4*)s;
  float4 v1 = *(const float4*)(s + 4);
  half8 h;
  h[0]=(half_t)v0.x; h[1]=(half_t)v0.y; h[2]=(half_t)v0.z; h[3]=(half_t)v0.w;
  h[4]=(half_t)v1.x; h[5]=(half_t)v1.y; h[6]=(half_t)v1.z; h[7]=(half_t)v1.w;
  *(half8*)(dst + (size_t)row * 640 + c8) = h;
}

// ---------- W [K][N] f32 -> Wt [Npad][K] f16 (zero-pad n >= N) ----------
__global__ __launch_bounds__(256) void k_transpose(const float* __restrict__ W,
                                                   half_t* __restrict__ Wt,
                                                   int K, int N, int total) {
  int i = blockIdx.x * 256 + threadIdx.x;
  if (i >= total) return;
  int n = i / K;
  int k = i - n * K;
  float v = (n < N) ? W[k * N + n] : 0.f;
  Wt[i] = (half_t)v;
}

// ---------- GEMM (layers 1&2): 128x128 tile, BK=64, fused stats, f16 out ----------
__global__ __launch_bounds__(256) void k_gemm(
    const half_t* __restrict__ A, int lda, int K,
    const half_t* __restrict__ Bt,
    const float* __restrict__ bias,
    half_t* __restrict__ o16, int ldo,
    float* __restrict__ ps, float* __restrict__ pq) {
  __shared__ __align__(16) char smem[32768];
  half_t* Asm = (half_t*)smem;            // [128][64] halfs, chunk-swizzled
  half_t* Bsm = (half_t*)(smem + 16384);
  const int tid  = threadIdx.x;
  const int lane = tid & 63;
  const int w    = tid >> 6;
  const int wr   = w >> 1, wc = w & 1;
  const int ml   = lane & 15, g = lane >> 4;
  const int brow = blockIdx.x * 128;
  const int bcol = blockIdx.y * 128;
  const int sr  = lane >> 3;
  const int scg = (lane & 7) ^ sr;

  f32x4 acc[4][4];
#pragma unroll
  for (int i = 0; i < 4; i++)
#pragma unroll
    for (int j = 0; j < 4; j++) acc[i][j] = (f32x4){0.f, 0.f, 0.f, 0.f};

  const half_t* Abase = A  + (size_t)brow * lda;
  const half_t* Bbase = Bt + (size_t)bcol * K;

  for (int k0 = 0; k0 < K; k0 += 64) {
    if (k0) __syncthreads();
#pragma unroll
    for (int it = 0; it < 4; it++) {
      int q = it * 4 + w;
      int r = q * 8 + sr;
      const half_t* ga = Abase + (size_t)r * lda + k0 + scg * 8;
      const half_t* gb = Bbase + (size_t)r * K   + k0 + scg * 8;
      __builtin_amdgcn_global_load_lds((AS1 const void*)ga, (AS3 void*)(Asm + q * 512), 16, 0, 0);
      __builtin_amdgcn_global_load_lds((AS1 const void*)gb, (AS3 void*)(Bsm + q * 512), 16, 0, 0);
    }
    __syncthreads();
#pragma unroll
    for (int kk = 0; kk < 64; kk += 16) {
      int k  = kk + g * 4;
      int cs = k >> 3;
      int ko = (k & 7) * 2;
      half4 af[4], bf[4];
#pragma unroll
      for (int fm = 0; fm < 4; fm++) {
        int row = wr * 64 + fm * 16 + ml;
        af[fm] = *(const half4*)((const char*)Asm + row * 128 + ((cs ^ (row & 7)) << 4) + ko);
      }
#pragma unroll
      for (int fn = 0; fn < 4; fn++) {
        int row = wc * 64 + fn * 16 + ml;
        bf[fn] = *(const half4*)((const char*)Bsm + row * 128 + ((cs ^ (row & 7)) << 4) + ko);
      }
#pragma unroll
      for (int fm = 0; fm < 4; fm++)
#pragma unroll
        for (int fn = 0; fn < 4; fn++)
          acc[fm][fn] = __builtin_amdgcn_mfma_f32_16x16x16f16(af[fm], bf[fn], acc[fm][fn], 0, 0, 0);
    }
  }
  __syncthreads();

#pragma unroll
  for (int fn = 0; fn < 4; fn++) {
    int col  = wc * 64 + fn * 16 + ml;
    int gcol = bcol + col;
    float bz = bias[gcol];
    float s = 0.f, q = 0.f;
#pragma unroll
    for (int fm = 0; fm < 4; fm++)
#pragma unroll
      for (int rr = 0; rr < 4; rr++) {
        float v = acc[fm][fn][rr] + bz;
        acc[fm][fn][rr] = v;
        s += v; q += v * v;
      }
    s += __shfl_xor(s, 16, 64); s += __shfl_xor(s, 32, 64);
    q += __shfl_xor(q, 16, 64); q += __shfl_xor(q, 32, 64);
    if (g == 0) {
      ps[(size_t)gcol * 1024 + blockIdx.x * 2 + wr] = s;
      pq[(size_t)gcol * 1024 + blockIdx.x * 2 + wr] = q;
    }
  }

  half_t* so = (half_t*)smem;  // [128][128]
#pragma unroll
  for (int fn = 0; fn < 4; fn++)
#pragma unroll
    for (int fm = 0; fm < 4; fm++)
#pragma unroll
      for (int rr = 0; rr < 4; rr++)
        so[(wr * 64 + fm * 16 + g * 4 + rr) * 128 + wc * 64 + fn * 16 + ml] =
            (half_t)acc[fm][fn][rr];
  __syncthreads();
#pragma unroll
  for (int it = 0; it < 8; it++) {
    int r = it * 16 + (tid >> 4);
    int c = (tid & 15) * 8;
    *(half8*)(o16 + (size_t)(brow + r) * ldo + bcol + c) = *(const half8*)&so[r * 128 + c];
  }
}

// ---------- BN finalize ----------
__global__ __launch_bounds__(256) void k_bnfinal(
    const float* __restrict__ ps, const float* __restrict__ pq,
    const float* __restrict__ gamma, const float* __restrict__ beta,
    float* __restrict__ sc, float* __restrict__ sh) {
  int c = blockIdx.x, t = threadIdx.x;
  float s = 0.f, q = 0.f;
#pragma unroll
  for (int i = 0; i < 4; i++) {
    s += ps[(size_t)c * 1024 + t + i * 256];
    q += pq[(size_t)c * 1024 + t + i * 256];
  }
#pragma unroll
  for (int o = 1; o < 64; o <<= 1) { s += __shfl_xor(s, o, 64); q += __shfl_xor(q, o, 64); }
  __shared__ float ss[4], qq[4];
  if ((t & 63) == 0) { ss[t >> 6] = s; qq[t >> 6] = q; }
  __syncthreads();
  if (t == 0) {
    s = ss[0] + ss[1] + ss[2] + ss[3];
    q = qq[0] + qq[1] + qq[2] + qq[3];
    float mu   = s * (1.f / NBATCH);
    float var  = fmaxf(q * (1.f / NBATCH) - mu * mu, 0.f);
    float rstd = rsqrtf(var + 1e-3f);
    float a = gamma[c] * rstd;
    sc[c] = a;
    sh[c] = beta[c] - mu * a;
  }
}

// ---------- in-place BN+ReLU on a 256-wide f16 slice of act ----------
__global__ __launch_bounds__(256) void k_bnrelu(half_t* __restrict__ p,
                                                const float* __restrict__ sc,
                                                const float* __restrict__ sh) {
  size_t i = (size_t)blockIdx.x * 256 + threadIdx.x;
  int row = (int)(i >> 5), c8 = (int)(i & 31) << 3;
  half_t* a = p + (size_t)row * 640 + c8;
  half8 v = *(const half8*)a;
  half8 o;
#pragma unroll
  for (int j = 0; j < 8; j++)
    o[j] = (half_t)fmaxf(fmaf((float)v[j], sc[c8 + j], sh[c8 + j]), 0.f);
  *(half8*)a = o;
}

// ---------- softmax helpers ----------
template<int L>
__device__ __forceinline__ void seg_rt(float* __restrict__ zr, int S) {
  float v[L];
#pragma unroll
  for (int j = 0; j < L; j++) v[j] = zr[S + j];
  float m0 = -1e30f, m1 = -1e30f, m2 = -1e30f, m3 = -1e30f;
#pragma unroll
  for (int j = 0; j < L; j++) {
    if ((j & 3) == 0) m0 = fmaxf(m0, v[j]);
    else if ((j & 3) == 1) m1 = fmaxf(m1, v[j]);
    else if ((j & 3) == 2) m2 = fmaxf(m2, v[j]);
    else m3 = fmaxf(m3, v[j]);
  }
  const float m = fmaxf(fmaxf(m0, m1), fmaxf(m2, m3));
  float s0 = 0.f, s1 = 0.f, s2 = 0.f, s3 = 0.f;
#pragma unroll
  for (int j = 0; j < L; j++) {
    float e = __expf(v[j] - m);
    v[j] = e;
    if ((j & 3) == 0) s0 += e;
    else if ((j & 3) == 1) s1 += e;
    else if ((j & 3) == 2) s2 += e;
    else s3 += e;
  }
  const float inv = 1.0f / ((s0 + s1) + (s2 + s3));
#pragma unroll
  for (int j = 0; j < L; j++) zr[S + j] = v[j] * inv;
}

template<int S, int L>
__device__ __forceinline__ void seg_split(float* __restrict__ zr, int par) {
  constexpr int H = L / 2;
  const int base = S + par * H;
  float v[H];
#pragma unroll
  for (int j = 0; j < H; j++) v[j] = zr[base + j];
  float m0 = -1e30f, m1 = -1e30f, m2 = -1e30f, m3 = -1e30f;
#pragma unroll
  for (int j = 0; j < H; j++) {
    if ((j & 3) == 0) m0 = fmaxf(m0, v[j]);
    else if ((j & 3) == 1) m1 = fmaxf(m1, v[j]);
    else if ((j & 3) == 2) m2 = fmaxf(m2, v[j]);
    else m3 = fmaxf(m3, v[j]);
  }
  float m = fmaxf(fmaxf(m0, m1), fmaxf(m2, m3));
  m = fmaxf(m, __shfl_xor(m, 1, 64));
  float s0 = 0.f, s1 = 0.f, s2 = 0.f, s3 = 0.f;
#pragma unroll
  for (int j = 0; j < H; j++) {
    float e = __expf(v[j] - m);
    v[j] = e;
    if ((j & 3) == 0) s0 += e;
    else if ((j & 3) == 1) s1 += e;
    else if ((j & 3) == 2) s2 += e;
    else s3 += e;
  }
  float s = (s0 + s1) + (s2 + s3);
  s += __shfl_xor(s, 1, 64);
  const float inv = 1.0f / s;
#pragma unroll
  for (int j = 0; j < H; j++) zr[base + j] = v[j] * inv;
}

__device__ __forceinline__ bool is_alpha(int c) {
  const unsigned long long AM0 =
      (1ull << 0) | (1ull << 11) | (1ull << 20) | (1ull << 31) | (1ull << 37) |
      (1ull << 48) | (1ull << 59);
  const unsigned long long AM1 = (1ull << 3) | (1ull << 14) | (1ull << 25);  // 67,78,89
  if (c >= 90) return false;
  return (((c < 64) ? (AM0 >> c) : (AM1 >> (c - 64))) & 1ull) != 0ull;
}

// ---------- fused GEMM3 + gumbel-softmax: 128 x 384 tile, 8 waves ----------
// A = act [B][640] f16; Bt = Wout^T [384][640] f16; out = final [B][366] f32.
__global__ __launch_bounds__(512, 2) void k_gemm3sm(
    const half_t* __restrict__ A,
    const half_t* __restrict__ Bt,
    const float* __restrict__ bias,
    const float* __restrict__ gum,
    float* __restrict__ out) {
  __shared__ __align__(16) char smem[65536];
  half_t* Asm = (half_t*)smem;             // [128][64] chunk-swizzled (16 KB)
  half_t* Bsm = (half_t*)(smem + 16384);   // [384][64] chunk-swizzled (48 KB)
  float (*zb)[373] = (float(*)[373])smem;  // epilogue: [32][373] (47.7 KB)
  const int tid  = threadIdx.x;
  const int lane = tid & 63;
  const int w    = tid >> 6;         // 0..7
  const int wr   = w >> 2;           // 0..1 : rows wr*64..+63
  const int wc   = w & 3;            // 0..3 : cols wc*96..+95
  const int ml   = lane & 15, g = lane >> 4;
  const int brow = blockIdx.x * 128;
  const int sr   = lane >> 3;
  const int scg  = (lane & 7) ^ sr;

  f32x4 acc[4][6];
#pragma unroll
  for (int i = 0; i < 4; i++)
#pragma unroll
    for (int j = 0; j < 6; j++) acc[i][j] = (f32x4){0.f, 0.f, 0.f, 0.f};

  const half_t* Abase = A + (size_t)brow * 640;

  for (int k0 = 0; k0 < 640; k0 += 64) {
    if (k0) __syncthreads();
    // stage A: 16 q-groups (2 per wave), B: 48 q-groups (6 per wave)
#pragma unroll
    for (int it = 0; it < 2; it++) {
      int q = it * 8 + w;
      int r = q * 8 + sr;
      const half_t* ga = Abase + (size_t)r * 640 + k0 + scg * 8;
      __builtin_amdgcn_global_load_lds((AS1 const void*)ga, (AS3 void*)(Asm + q * 512), 16, 0, 0);
    }
#pragma unroll
    for (int it = 0; it < 6; it++) {
      int q = it * 8 + w;
      int r = q * 8 + sr;
      const half_t* gb = Bt + (size_t)r * 640 + k0 + scg * 8;
      __builtin_amdgcn_global_load_lds((AS1 const void*)gb, (AS3 void*)(Bsm + q * 512), 16, 0, 0);
    }
    __syncthreads();
#pragma unroll
    for (int kk = 0; kk < 64; kk += 16) {
      int k  = kk + g * 4;
      int cs = k >> 3;
      int ko = (k & 7) * 2;
      half4 af[4], bf[6];
#pragma unroll
      for (int fm = 0; fm < 4; fm++) {
        int row = wr * 64 + fm * 16 + ml;
        af[fm] = *(const half4*)((const char*)Asm + row * 128 + ((cs ^ (row & 7)) << 4) + ko);
      }
#pragma unroll
      for (int fn = 0; fn < 6; fn++) {
        int row = wc * 96 + fn * 16 + ml;
        bf[fn] = *(const half4*)((const char*)Bsm + row * 128 + ((cs ^ (row & 7)) << 4) + ko);
      }
#pragma unroll
      for (int fm = 0; fm < 4; fm++)
#pragma unroll
        for (int fn = 0; fn < 6; fn++)
          acc[fm][fn] = __builtin_amdgcn_mfma_f32_16x16x16f16(af[fm], bf[fn], acc[fm][fn], 0, 0, 0);
    }
  }

  // ---- epilogue: 4 batches of 32 rows through zb ----
  for (int b = 0; b < 4; b++) {
    __syncthreads();   // stage LDS / previous batch done
    if (wr == (b >> 1)) {
      const int fmb = (b & 1) * 2;
#pragma unroll
      for (int fl = 0; fl < 2; fl++) {
#pragma unroll
        for (int fn = 0; fn < 6; fn++) {
          int col = wc * 96 + fn * 16 + ml;
          if (col < 366) {
            float bz = bias[col];
#pragma unroll
            for (int rr = 0; rr < 4; rr++)
              zb[fl * 16 + g * 4 + rr][col] = acc[fmb + fl][fn][rr] + bz;
          }
        }
      }
    }
    __syncthreads();
    // gumbel transform / tanh (coalesced g read)
    const size_t gbase = (size_t)(brow + b * 32) * 366;
    for (int i2 = tid; i2 < 32 * 183; i2 += 512) {
      int e0 = i2 * 2;
      int r = e0 / 366;
      int c = e0 - r * 366;
      float2 gg = *(const float2*)(gum + gbase + e0);
      float vx = zb[r][c], vy = zb[r][c + 1];
      zb[r][c]     = is_alpha(c)     ? tanhf(vx) : (vx + gg.x) * 5.0f;
      zb[r][c + 1] = is_alpha(c + 1) ? tanhf(vy) : (vy + gg.y) * 5.0f;
    }
    __syncthreads();
    {
      const int par = lane & 1;
      float* zr = &zb[lane >> 1][0];
      switch (w) {
        case 0: seg_split<184, 100>(zr, par); break;
        case 1: seg_split<120, 50>(zr, par); break;
        case 2: seg_split<314, 30>(zr, par);
                { int sa = par ? 174 : 100; seg_rt<2>(zr, sa); } break;
        case 3: { int sa = par ? 68 : 1;   int sb = par ? 176 : 12;
                  seg_rt<10>(zr, sa); seg_rt<8>(zr, sb); } break;
        case 4: { int sa = par ? 79 : 21;  int sb = par ? 359 : 60;
                  seg_rt<10>(zr, sa); seg_rt<7>(zr, sb); } break;
        case 5: { int sa = par ? 90 : 38;  int sb = par ? 102 : 32; int sd = par ? 292 : 117;
                  seg_rt<10>(zr, sa); seg_rt<5>(zr, sb); seg_rt<3>(zr, sd); } break;
        case 6: { int sa = par ? 107 : 49; int sb = par ? 344 : 170; int sd = par ? 312 : 290;
                  seg_rt<10>(zr, sa); seg_rt<4>(zr, sb); seg_rt<2>(zr, sd); } break;
        default:
          if (par == 0) { seg_rt<12>(zr, 295); seg_rt<5>(zr, 307); }
          else          { seg_rt<9>(zr, 348);  seg_rt<6>(zr, 284); seg_rt<2>(zr, 357); }
          break;
      }
    }
    __syncthreads();
    for (int i2 = tid; i2 < 32 * 183; i2 += 512) {
      int e0 = i2 * 2;
      int r = e0 / 366;
      float2 o;
      o.x = zb[r][e0 - r * 366];
      o.y = zb[r][e0 - r * 366 + 1];
      *(float2*)(out + gbase + e0) = o;
    }
  }
}

extern "C" void kernel_launch(void* const* d_in, const int* in_sizes, int n_in,
                              void* d_out, int out_size, void* d_ws, size_t ws_size,
                              hipStream_t stream) {
  const float* z      = (const float*)d_in[0];
  const float* g      = (const float*)d_in[1];
  const float* W1     = (const float*)d_in[2];
  const float* b1     = (const float*)d_in[3];
  const float* gamma1 = (const float*)d_in[4];
  const float* beta1  = (const float*)d_in[5];
  const float* W2     = (const float*)d_in[6];
  const float* b2     = (const float*)d_in[7];
  const float* gamma2 = (const float*)d_in[8];
  const float* beta2  = (const float*)d_in[9];
  const float* Wout   = (const float*)d_in[10];
  const float* bout   = (const float*)d_in[11];
  float* out = (float*)d_out;
  char* ws = (char*)d_ws;

  size_t off = 0;
  half_t* act = (half_t*)(ws + off); off += (size_t)NBATCH * 640 * 2;  // [B][p2|p1|z]
  half_t* W1t = (half_t*)(ws + off); off += (size_t)256 * 128 * 2;
  half_t* W2t = (half_t*)(ws + off); off += (size_t)256 * 384 * 2;
  half_t* Wot = (half_t*)(ws + off); off += (size_t)384 * 640 * 2;
  float*  ps  = (float*)(ws + off);  off += (size_t)256 * 1024 * 4;
  float*  pq  = (float*)(ws + off);  off += (size_t)256 * 1024 * 4;
  float*  sc1 = (float*)(ws + off);  off += 256 * 4;
  float*  sh1 = (float*)(ws + off);  off += 256 * 4;
  float*  sc2 = (float*)(ws + off);  off += 256 * 4;
  float*  sh2 = (float*)(ws + off);  off += 256 * 4;
  (void)ws_size; (void)in_sizes; (void)n_in; (void)out_size;

  // prep: z into act cols 512..639, transposed f16 weights
  k_cvtz<<<4096, 256, 0, stream>>>(z, act + 512);
  k_transpose<<<(256 * 128 + 255) / 256, 256, 0, stream>>>(W1, W1t, 128, 256, 256 * 128);
  k_transpose<<<(256 * 384 + 255) / 256, 256, 0, stream>>>(W2, W2t, 384, 256, 256 * 384);
  k_transpose<<<(384 * 640 + 255) / 256, 256, 0, stream>>>(Wout, Wot, 640, 366, 384 * 640);

  // layer 1: h1(f16, act cols 256..511) = z @ W1 + b1, fused stats
  k_gemm<<<dim3(512, 2), 256, 0, stream>>>(act + 512, 640, 128, W1t, b1,
                                           act + 256, 640, ps, pq);
  k_bnfinal<<<256, 256, 0, stream>>>(ps, pq, gamma1, beta1, sc1, sh1);
  k_bnrelu<<<8192, 256, 0, stream>>>(act + 256, sc1, sh1);

  // layer 2: h2(f16, act cols 0..255) = [p1|z] @ W2 + b2, fused stats
  k_gemm<<<dim3(512, 2), 256, 0, stream>>>(act + 256, 640, 384, W2t, b2,
                                           act + 0, 640, ps, pq);
  k_bnfinal<<<256, 256, 0, stream>>>(ps, pq, gamma2, beta2, sc2, sh2);
  k_bnrelu<<<8192, 256, 0, stream>>>(act + 0, sc2, sh2);

  // fused output layer + gumbel-softmax -> d_out
  k_gemm3sm<<<512, 512, 0, stream>>>(act, Wot, bout, g, out);
}

// Round 7
// 246.567 us; speedup vs baseline: 1.5904x; 1.5904x over previous
//
#include <hip/hip_runtime.h>

typedef _Float16 half_t;
typedef _Float16 half4 __attribute__((ext_vector_type(4)));
typedef _Float16 half8 __attribute__((ext_vector_type(8)));
typedef float f32x4 __attribute__((ext_vector_type(4)));

#define AS1 __attribute__((address_space(1)))
#define AS3 __attribute__((address_space(3)))

static constexpr int NBATCH = 65536;

// ---------- z f32 -> f16 into act[:,512:640] ----------
__global__ __launch_bounds__(256) void k_cvtz(const float* __restrict__ z,
                                              half_t* __restrict__ dst) {
  size_t i = (size_t)blockIdx.x * 256 + threadIdx.x;
  int row = (int)(i >> 4), c8 = (int)(i & 15) << 3;
  const float* s = z + (size_t)row * 128 + c8;
  float4 v0 = *(const float4*)s;
  float4 v1 = *(const float4*)(s + 4);
  half8 h;
  h[0]=(half_t)v0.x; h[1]=(half_t)v0.y; h[2]=(half_t)v0.z; h[3]=(half_t)v0.w;
  h[4]=(half_t)v1.x; h[5]=(half_t)v1.y; h[6]=(half_t)v1.z; h[7]=(half_t)v1.w;
  *(half8*)(dst + (size_t)row * 640 + c8) = h;
}

// ---------- W [K][N] f32 -> Wt [Npad][K] f16 (zero-pad n >= N) ----------
__global__ __launch_bounds__(256) void k_transpose(const float* __restrict__ W,
                                                   half_t* __restrict__ Wt,
                                                   int K, int N, int total) {
  int i = blockIdx.x * 256 + threadIdx.x;
  if (i >= total) return;
  int n = i / K;
  int k = i - n * K;
  float v = (n < N) ? W[k * N + n] : 0.f;
  Wt[i] = (half_t)v;
}

// ---------- GEMM (layers 1&2): 128x128 tile, BK=64, fused stats, f16 out ----------
__global__ __launch_bounds__(256) void k_gemm(
    const half_t* __restrict__ A, int lda, int K,
    const half_t* __restrict__ Bt,
    const float* __restrict__ bias,
    half_t* __restrict__ o16, int ldo,
    float* __restrict__ ps, float* __restrict__ pq) {
  __shared__ __align__(16) char smem[32768];
  half_t* Asm = (half_t*)smem;            // [128][64] halfs, chunk-swizzled
  half_t* Bsm = (half_t*)(smem + 16384);
  const int tid  = threadIdx.x;
  const int lane = tid & 63;
  const int w    = tid >> 6;
  const int wr   = w >> 1, wc = w & 1;
  const int ml   = lane & 15, g = lane >> 4;
  const int brow = blockIdx.x * 128;
  const int bcol = blockIdx.y * 128;
  const int sr  = lane >> 3;
  const int scg = (lane & 7) ^ sr;

  f32x4 acc[4][4];
#pragma unroll
  for (int i = 0; i < 4; i++)
#pragma unroll
    for (int j = 0; j < 4; j++) acc[i][j] = (f32x4){0.f, 0.f, 0.f, 0.f};

  const half_t* Abase = A  + (size_t)brow * lda;
  const half_t* Bbase = Bt + (size_t)bcol * K;

  for (int k0 = 0; k0 < K; k0 += 64) {
    if (k0) __syncthreads();
#pragma unroll
    for (int it = 0; it < 4; it++) {
      int q = it * 4 + w;
      int r = q * 8 + sr;
      const half_t* ga = Abase + (size_t)r * lda + k0 + scg * 8;
      const half_t* gb = Bbase + (size_t)r * K   + k0 + scg * 8;
      __builtin_amdgcn_global_load_lds((AS1 const void*)ga, (AS3 void*)(Asm + q * 512), 16, 0, 0);
      __builtin_amdgcn_global_load_lds((AS1 const void*)gb, (AS3 void*)(Bsm + q * 512), 16, 0, 0);
    }
    __syncthreads();
#pragma unroll
    for (int kk = 0; kk < 64; kk += 16) {
      int k  = kk + g * 4;
      int cs = k >> 3;
      int ko = (k & 7) * 2;
      half4 af[4], bf[4];
#pragma unroll
      for (int fm = 0; fm < 4; fm++) {
        int row = wr * 64 + fm * 16 + ml;
        af[fm] = *(const half4*)((const char*)Asm + row * 128 + ((cs ^ (row & 7)) << 4) + ko);
      }
#pragma unroll
      for (int fn = 0; fn < 4; fn++) {
        int row = wc * 64 + fn * 16 + ml;
        bf[fn] = *(const half4*)((const char*)Bsm + row * 128 + ((cs ^ (row & 7)) << 4) + ko);
      }
#pragma unroll
      for (int fm = 0; fm < 4; fm++)
#pragma unroll
        for (int fn = 0; fn < 4; fn++)
          acc[fm][fn] = __builtin_amdgcn_mfma_f32_16x16x16f16(af[fm], bf[fn], acc[fm][fn], 0, 0, 0);
    }
  }
  __syncthreads();

#pragma unroll
  for (int fn = 0; fn < 4; fn++) {
    int col  = wc * 64 + fn * 16 + ml;
    int gcol = bcol + col;
    float bz = bias[gcol];
    float s = 0.f, q = 0.f;
#pragma unroll
    for (int fm = 0; fm < 4; fm++)
#pragma unroll
      for (int rr = 0; rr < 4; rr++) {
        float v = acc[fm][fn][rr] + bz;
        acc[fm][fn][rr] = v;
        s += v; q += v * v;
      }
    s += __shfl_xor(s, 16, 64); s += __shfl_xor(s, 32, 64);
    q += __shfl_xor(q, 16, 64); q += __shfl_xor(q, 32, 64);
    if (g == 0) {
      ps[(size_t)gcol * 1024 + blockIdx.x * 2 + wr] = s;
      pq[(size_t)gcol * 1024 + blockIdx.x * 2 + wr] = q;
    }
  }

  half_t* so = (half_t*)smem;  // [128][128]
#pragma unroll
  for (int fn = 0; fn < 4; fn++)
#pragma unroll
    for (int fm = 0; fm < 4; fm++)
#pragma unroll
      for (int rr = 0; rr < 4; rr++)
        so[(wr * 64 + fm * 16 + g * 4 + rr) * 128 + wc * 64 + fn * 16 + ml] =
            (half_t)acc[fm][fn][rr];
  __syncthreads();
#pragma unroll
  for (int it = 0; it < 8; it++) {
    int r = it * 16 + (tid >> 4);
    int c = (tid & 15) * 8;
    *(half8*)(o16 + (size_t)(brow + r) * ldo + bcol + c) = *(const half8*)&so[r * 128 + c];
  }
}

// ---------- BN finalize ----------
__global__ __launch_bounds__(256) void k_bnfinal(
    const float* __restrict__ ps, const float* __restrict__ pq,
    const float* __restrict__ gamma, const float* __restrict__ beta,
    float* __restrict__ sc, float* __restrict__ sh) {
  int c = blockIdx.x, t = threadIdx.x;
  float s = 0.f, q = 0.f;
#pragma unroll
  for (int i = 0; i < 4; i++) {
    s += ps[(size_t)c * 1024 + t + i * 256];
    q += pq[(size_t)c * 1024 + t + i * 256];
  }
#pragma unroll
  for (int o = 1; o < 64; o <<= 1) { s += __shfl_xor(s, o, 64); q += __shfl_xor(q, o, 64); }
  __shared__ float ss[4], qq[4];
  if ((t & 63) == 0) { ss[t >> 6] = s; qq[t >> 6] = q; }
  __syncthreads();
  if (t == 0) {
    s = ss[0] + ss[1] + ss[2] + ss[3];
    q = qq[0] + qq[1] + qq[2] + qq[3];
    float mu   = s * (1.f / NBATCH);
    float var  = fmaxf(q * (1.f / NBATCH) - mu * mu, 0.f);
    float rstd = rsqrtf(var + 1e-3f);
    float a = gamma[c] * rstd;
    sc[c] = a;
    sh[c] = beta[c] - mu * a;
  }
}

// ---------- in-place BN+ReLU on a 256-wide f16 slice of act ----------
__global__ __launch_bounds__(256) void k_bnrelu(half_t* __restrict__ p,
                                                const float* __restrict__ sc,
                                                const float* __restrict__ sh) {
  size_t i = (size_t)blockIdx.x * 256 + threadIdx.x;
  int row = (int)(i >> 5), c8 = (int)(i & 31) << 3;
  half_t* a = p + (size_t)row * 640 + c8;
  half8 v = *(const half8*)a;
  half8 o;
#pragma unroll
  for (int j = 0; j < 8; j++)
    o[j] = (half_t)fmaxf(fmaf((float)v[j], sc[c8 + j], sh[c8 + j]), 0.f);
  *(half8*)a = o;
}

// ---------- softmax helpers ----------
template<int L>
__device__ __forceinline__ void seg_rt(float* __restrict__ zr, int S) {
  float v[L];
#pragma unroll
  for (int j = 0; j < L; j++) v[j] = zr[S + j];
  float m0 = -1e30f, m1 = -1e30f, m2 = -1e30f, m3 = -1e30f;
#pragma unroll
  for (int j = 0; j < L; j++) {
    if ((j & 3) == 0) m0 = fmaxf(m0, v[j]);
    else if ((j & 3) == 1) m1 = fmaxf(m1, v[j]);
    else if ((j & 3) == 2) m2 = fmaxf(m2, v[j]);
    else m3 = fmaxf(m3, v[j]);
  }
  const float m = fmaxf(fmaxf(m0, m1), fmaxf(m2, m3));
  float s0 = 0.f, s1 = 0.f, s2 = 0.f, s3 = 0.f;
#pragma unroll
  for (int j = 0; j < L; j++) {
    float e = __expf(v[j] - m);
    v[j] = e;
    if ((j & 3) == 0) s0 += e;
    else if ((j & 3) == 1) s1 += e;
    else if ((j & 3) == 2) s2 += e;
    else s3 += e;
  }
  const float inv = 1.0f / ((s0 + s1) + (s2 + s3));
#pragma unroll
  for (int j = 0; j < L; j++) zr[S + j] = v[j] * inv;
}

template<int S, int L>
__device__ __forceinline__ void seg_split(float* __restrict__ zr, int par) {
  constexpr int H = L / 2;
  const int base = S + par * H;
  float v[H];
#pragma unroll
  for (int j = 0; j < H; j++) v[j] = zr[base + j];
  float m0 = -1e30f, m1 = -1e30f, m2 = -1e30f, m3 = -1e30f;
#pragma unroll
  for (int j = 0; j < H; j++) {
    if ((j & 3) == 0) m0 = fmaxf(m0, v[j]);
    else if ((j & 3) == 1) m1 = fmaxf(m1, v[j]);
    else if ((j & 3) == 2) m2 = fmaxf(m2, v[j]);
    else m3 = fmaxf(m3, v[j]);
  }
  float m = fmaxf(fmaxf(m0, m1), fmaxf(m2, m3));
  m = fmaxf(m, __shfl_xor(m, 1, 64));
  float s0 = 0.f, s1 = 0.f, s2 = 0.f, s3 = 0.f;
#pragma unroll
  for (int j = 0; j < H; j++) {
    float e = __expf(v[j] - m);
    v[j] = e;
    if ((j & 3) == 0) s0 += e;
    else if ((j & 3) == 1) s1 += e;
    else if ((j & 3) == 2) s2 += e;
    else s3 += e;
  }
  float s = (s0 + s1) + (s2 + s3);
  s += __shfl_xor(s, 1, 64);
  const float inv = 1.0f / s;
#pragma unroll
  for (int j = 0; j < H; j++) zr[base + j] = v[j] * inv;
}

__device__ __forceinline__ bool is_alpha(int c) {
  const unsigned long long AM0 =
      (1ull << 0) | (1ull << 11) | (1ull << 20) | (1ull << 31) | (1ull << 37) |
      (1ull << 48) | (1ull << 59);
  const unsigned long long AM1 = (1ull << 3) | (1ull << 14) | (1ull << 25);  // 67,78,89
  if (c >= 90) return false;
  return (((c < 64) ? (AM0 >> c) : (AM1 >> (c - 64))) & 1ull) != 0ull;
}

// ---------- fused GEMM3 + gumbel-softmax: 128 x 384 tile, 8 waves ----------
// A = act [B][640] f16; Bt = Wout^T [384][640] f16; out = final [B][366] f32.
__global__ __launch_bounds__(512, 2) void k_gemm3sm(
    const half_t* __restrict__ A,
    const half_t* __restrict__ Bt,
    const float* __restrict__ bias,
    const float* __restrict__ gum,
    float* __restrict__ out) {
  __shared__ __align__(16) char smem[65536];
  half_t* Asm = (half_t*)smem;             // [128][64] chunk-swizzled (16 KB)
  half_t* Bsm = (half_t*)(smem + 16384);   // [384][64] chunk-swizzled (48 KB)
  float (*zb)[373] = (float(*)[373])smem;  // epilogue: [32][373] (47.7 KB)
  const int tid  = threadIdx.x;
  const int lane = tid & 63;
  const int w    = tid >> 6;         // 0..7
  const int wr   = w >> 2;           // 0..1 : rows wr*64..+63
  const int wc   = w & 3;            // 0..3 : cols wc*96..+95
  const int ml   = lane & 15, g = lane >> 4;
  const int brow = blockIdx.x * 128;
  const int sr   = lane >> 3;
  const int scg  = (lane & 7) ^ sr;

  f32x4 acc[4][6];
#pragma unroll
  for (int i = 0; i < 4; i++)
#pragma unroll
    for (int j = 0; j < 6; j++) acc[i][j] = (f32x4){0.f, 0.f, 0.f, 0.f};

  const half_t* Abase = A + (size_t)brow * 640;

  for (int k0 = 0; k0 < 640; k0 += 64) {
    if (k0) __syncthreads();
    // stage A: 16 q-groups (2 per wave), B: 48 q-groups (6 per wave)
#pragma unroll
    for (int it = 0; it < 2; it++) {
      int q = it * 8 + w;
      int r = q * 8 + sr;
      const half_t* ga = Abase + (size_t)r * 640 + k0 + scg * 8;
      __builtin_amdgcn_global_load_lds((AS1 const void*)ga, (AS3 void*)(Asm + q * 512), 16, 0, 0);
    }
#pragma unroll
    for (int it = 0; it < 6; it++) {
      int q = it * 8 + w;
      int r = q * 8 + sr;
      const half_t* gb = Bt + (size_t)r * 640 + k0 + scg * 8;
      __builtin_amdgcn_global_load_lds((AS1 const void*)gb, (AS3 void*)(Bsm + q * 512), 16, 0, 0);
    }
    __syncthreads();
#pragma unroll
    for (int kk = 0; kk < 64; kk += 16) {
      int k  = kk + g * 4;
      int cs = k >> 3;
      int ko = (k & 7) * 2;
      half4 af[4], bf[6];
#pragma unroll
      for (int fm = 0; fm < 4; fm++) {
        int row = wr * 64 + fm * 16 + ml;
        af[fm] = *(const half4*)((const char*)Asm + row * 128 + ((cs ^ (row & 7)) << 4) + ko);
      }
#pragma unroll
      for (int fn = 0; fn < 6; fn++) {
        int row = wc * 96 + fn * 16 + ml;
        bf[fn] = *(const half4*)((const char*)Bsm + row * 128 + ((cs ^ (row & 7)) << 4) + ko);
      }
#pragma unroll
      for (int fm = 0; fm < 4; fm++)
#pragma unroll
        for (int fn = 0; fn < 6; fn++)
          acc[fm][fn] = __builtin_amdgcn_mfma_f32_16x16x16f16(af[fm], bf[fn], acc[fm][fn], 0, 0, 0);
    }
  }

  // ---- epilogue: 4 batches of 32 rows through zb ----
  // FULLY UNROLLED: every acc[][] index must be compile-time (rule #20 —
  // runtime-indexed ext_vector arrays spill to scratch; R6 regression).
#pragma unroll
  for (int b = 0; b < 4; b++) {
    __syncthreads();   // stage LDS / previous batch done
    if (wr == (b >> 1)) {
      const int fmb = (b & 1) * 2;
#pragma unroll
      for (int fl = 0; fl < 2; fl++) {
#pragma unroll
        for (int fn = 0; fn < 6; fn++) {
          int col = wc * 96 + fn * 16 + ml;
          if (col < 366) {
            float bz = bias[col];
#pragma unroll
            for (int rr = 0; rr < 4; rr++)
              zb[fl * 16 + g * 4 + rr][col] = acc[fmb + fl][fn][rr] + bz;
          }
        }
      }
    }
    __syncthreads();
    // gumbel transform / tanh (coalesced g read)
    const size_t gbase = (size_t)(brow + b * 32) * 366;
    for (int i2 = tid; i2 < 32 * 183; i2 += 512) {
      int e0 = i2 * 2;
      int r = e0 / 366;
      int c = e0 - r * 366;
      float2 gg = *(const float2*)(gum + gbase + e0);
      float vx = zb[r][c], vy = zb[r][c + 1];
      zb[r][c]     = is_alpha(c)     ? tanhf(vx) : (vx + gg.x) * 5.0f;
      zb[r][c + 1] = is_alpha(c + 1) ? tanhf(vy) : (vy + gg.y) * 5.0f;
    }
    __syncthreads();
    {
      const int par = lane & 1;
      float* zr = &zb[lane >> 1][0];
      switch (w) {
        case 0: seg_split<184, 100>(zr, par); break;
        case 1: seg_split<120, 50>(zr, par); break;
        case 2: seg_split<314, 30>(zr, par);
                { int sa = par ? 174 : 100; seg_rt<2>(zr, sa); } break;
        case 3: { int sa = par ? 68 : 1;   int sb = par ? 176 : 12;
                  seg_rt<10>(zr, sa); seg_rt<8>(zr, sb); } break;
        case 4: { int sa = par ? 79 : 21;  int sb = par ? 359 : 60;
                  seg_rt<10>(zr, sa); seg_rt<7>(zr, sb); } break;
        case 5: { int sa = par ? 90 : 38;  int sb = par ? 102 : 32; int sd = par ? 292 : 117;
                  seg_rt<10>(zr, sa); seg_rt<5>(zr, sb); seg_rt<3>(zr, sd); } break;
        case 6: { int sa = par ? 107 : 49; int sb = par ? 344 : 170; int sd = par ? 312 : 290;
                  seg_rt<10>(zr, sa); seg_rt<4>(zr, sb); seg_rt<2>(zr, sd); } break;
        default:
          if (par == 0) { seg_rt<12>(zr, 295); seg_rt<5>(zr, 307); }
          else          { seg_rt<9>(zr, 348);  seg_rt<6>(zr, 284); seg_rt<2>(zr, 357); }
          break;
      }
    }
    __syncthreads();
    for (int i2 = tid; i2 < 32 * 183; i2 += 512) {
      int e0 = i2 * 2;
      int r = e0 / 366;
      float2 o;
      o.x = zb[r][e0 - r * 366];
      o.y = zb[r][e0 - r * 366 + 1];
      *(float2*)(out + gbase + e0) = o;
    }
  }
}

extern "C" void kernel_launch(void* const* d_in, const int* in_sizes, int n_in,
                              void* d_out, int out_size, void* d_ws, size_t ws_size,
                              hipStream_t stream) {
  const float* z      = (const float*)d_in[0];
  const float* g      = (const float*)d_in[1];
  const float* W1     = (const float*)d_in[2];
  const float* b1     = (const float*)d_in[3];
  const float* gamma1 = (const float*)d_in[4];
  const float* beta1  = (const float*)d_in[5];
  const float* W2     = (const float*)d_in[6];
  const float* b2     = (const float*)d_in[7];
  const float* gamma2 = (const float*)d_in[8];
  const float* beta2  = (const float*)d_in[9];
  const float* Wout   = (const float*)d_in[10];
  const float* bout   = (const float*)d_in[11];
  float* out = (float*)d_out;
  char* ws = (char*)d_ws;

  size_t off = 0;
  half_t* act = (half_t*)(ws + off); off += (size_t)NBATCH * 640 * 2;  // [B][p2|p1|z]
  half_t* W1t = (half_t*)(ws + off); off += (size_t)256 * 128 * 2;
  half_t* W2t = (half_t*)(ws + off); off += (size_t)256 * 384 * 2;
  half_t* Wot = (half_t*)(ws + off); off += (size_t)384 * 640 * 2;
  float*  ps  = (float*)(ws + off);  off += (size_t)256 * 1024 * 4;
  float*  pq  = (float*)(ws + off);  off += (size_t)256 * 1024 * 4;
  float*  sc1 = (float*)(ws + off);  off += 256 * 4;
  float*  sh1 = (float*)(ws + off);  off += 256 * 4;
  float*  sc2 = (float*)(ws + off);  off += 256 * 4;
  float*  sh2 = (float*)(ws + off);  off += 256 * 4;
  (void)ws_size; (void)in_sizes; (void)n_in; (void)out_size;

  // prep: z into act cols 512..639, transposed f16 weights
  k_cvtz<<<4096, 256, 0, stream>>>(z, act + 512);
  k_transpose<<<(256 * 128 + 255) / 256, 256, 0, stream>>>(W1, W1t, 128, 256, 256 * 128);
  k_transpose<<<(256 * 384 + 255) / 256, 256, 0, stream>>>(W2, W2t, 384, 256, 256 * 384);
  k_transpose<<<(384 * 640 + 255) / 256, 256, 0, stream>>>(Wout, Wot, 640, 366, 384 * 640);

  // layer 1: h1(f16, act cols 256..511) = z @ W1 + b1, fused stats
  k_gemm<<<dim3(512, 2), 256, 0, stream>>>(act + 512, 640, 128, W1t, b1,
                                           act + 256, 640, ps, pq);
  k_bnfinal<<<256, 256, 0, stream>>>(ps, pq, gamma1, beta1, sc1, sh1);
  k_bnrelu<<<8192, 256, 0, stream>>>(act + 256, sc1, sh1);

  // layer 2: h2(f16, act cols 0..255) = [p1|z] @ W2 + b2, fused stats
  k_gemm<<<dim3(512, 2), 256, 0, stream>>>(act + 256, 640, 384, W2t, b2,
                                           act + 0, 640, ps, pq);
  k_bnfinal<<<256, 256, 0, stream>>>(ps, pq, gamma2, beta2, sc2, sh2);
  k_bnrelu<<<8192, 256, 0, stream>>>(act + 0, sc2, sh2);

  // fused output layer + gumbel-softmax -> d_out
  k_gemm3sm<<<512, 512, 0, stream>>>(act, Wot, bout, g, out);
}

// Round 8
// 215.060 us; speedup vs baseline: 1.8234x; 1.1465x over previous
//
#include <hip/hip_runtime.h>

typedef _Float16 half_t;
typedef _Float16 half4 __attribute__((ext_vector_type(4)));
typedef _Float16 half8 __attribute__((ext_vector_type(8)));
typedef float f32x4 __attribute__((ext_vector_type(4)));

#define AS1 __attribute__((address_space(1)))
#define AS3 __attribute__((address_space(3)))

static constexpr int NBATCH = 65536;

// ---------- z f32 -> f16 into act[:,512:640] ----------
__global__ __launch_bounds__(256) void k_cvtz(const float* __restrict__ z,
                                              half_t* __restrict__ dst) {
  size_t i = (size_t)blockIdx.x * 256 + threadIdx.x;
  int row = (int)(i >> 4), c8 = (int)(i & 15) << 3;
  const float* s = z + (size_t)row * 128 + c8;
  float4 v0 = *(const float4*)s;
  float4 v1 = *(const float4*)(s + 4);
  half8 h;
  h[0]=(half_t)v0.x; h[1]=(half_t)v0.y; h[2]=(half_t)v0.z; h[3]=(half_t)v0.w;
  h[4]=(half_t)v1.x; h[5]=(half_t)v1.y; h[6]=(half_t)v1.z; h[7]=(half_t)v1.w;
  *(half8*)(dst + (size_t)row * 640 + c8) = h;
}

// ---------- W [K][N] f32 -> Wt [Npad][K] f16 (zero-pad n >= N) ----------
__global__ __launch_bounds__(256) void k_transpose(const float* __restrict__ W,
                                                   half_t* __restrict__ Wt,
                                                   int K, int N, int total) {
  int i = blockIdx.x * 256 + threadIdx.x;
  if (i >= total) return;
  int n = i / K;
  int k = i - n * K;
  float v = (n < N) ? W[k * N + n] : 0.f;
  Wt[i] = (half_t)v;
}

// ---------- GEMM: 128x128 tile, BK=64, global_load_lds + XOR-chunk swizzle ----------
template<bool STATS, bool F16OUT>
__global__ __launch_bounds__(256) void k_gemm(
    const half_t* __restrict__ A, int lda, int K,
    const half_t* __restrict__ Bt,
    const float* __restrict__ bias,
    half_t* __restrict__ o16, float* __restrict__ o32, int ldo, int ncreal,
    float* __restrict__ ps, float* __restrict__ pq) {
  __shared__ __align__(16) char smem[32768];
  half_t* Asm = (half_t*)smem;            // [128][64] halfs, chunk-swizzled
  half_t* Bsm = (half_t*)(smem + 16384);
  const int tid  = threadIdx.x;
  const int lane = tid & 63;
  const int w    = tid >> 6;
  const int wr   = w >> 1, wc = w & 1;
  const int ml   = lane & 15, g = lane >> 4;
  const int brow = blockIdx.x * 128;
  const int bcol = blockIdx.y * 128;
  const int sr  = lane >> 3;
  const int scg = (lane & 7) ^ sr;

  f32x4 acc[4][4];
#pragma unroll
  for (int i = 0; i < 4; i++)
#pragma unroll
    for (int j = 0; j < 4; j++) acc[i][j] = (f32x4){0.f, 0.f, 0.f, 0.f};

  const half_t* Abase = A  + (size_t)brow * lda;
  const half_t* Bbase = Bt + (size_t)bcol * K;

  for (int k0 = 0; k0 < K; k0 += 64) {
    if (k0) __syncthreads();
#pragma unroll
    for (int it = 0; it < 4; it++) {
      int q = it * 4 + w;
      int r = q * 8 + sr;
      const half_t* ga = Abase + (size_t)r * lda + k0 + scg * 8;
      const half_t* gb = Bbase + (size_t)r * K   + k0 + scg * 8;
      __builtin_amdgcn_global_load_lds((AS1 const void*)ga, (AS3 void*)(Asm + q * 512), 16, 0, 0);
      __builtin_amdgcn_global_load_lds((AS1 const void*)gb, (AS3 void*)(Bsm + q * 512), 16, 0, 0);
    }
    __syncthreads();
#pragma unroll
    for (int kk = 0; kk < 64; kk += 16) {
      int k  = kk + g * 4;
      int cs = k >> 3;
      int ko = (k & 7) * 2;
      half4 af[4], bf[4];
#pragma unroll
      for (int fm = 0; fm < 4; fm++) {
        int row = wr * 64 + fm * 16 + ml;
        af[fm] = *(const half4*)((const char*)Asm + row * 128 + ((cs ^ (row & 7)) << 4) + ko);
      }
#pragma unroll
      for (int fn = 0; fn < 4; fn++) {
        int row = wc * 64 + fn * 16 + ml;
        bf[fn] = *(const half4*)((const char*)Bsm + row * 128 + ((cs ^ (row & 7)) << 4) + ko);
      }
#pragma unroll
      for (int fm = 0; fm < 4; fm++)
#pragma unroll
        for (int fn = 0; fn < 4; fn++)
          acc[fm][fn] = __builtin_amdgcn_mfma_f32_16x16x16f16(af[fm], bf[fn], acc[fm][fn], 0, 0, 0);
    }
  }
  __syncthreads();

#pragma unroll
  for (int fn = 0; fn < 4; fn++) {
    int col  = wc * 64 + fn * 16 + ml;
    int gcol = bcol + col;
    float bz = (gcol < ncreal) ? bias[gcol] : 0.f;
    float s = 0.f, q = 0.f;
#pragma unroll
    for (int fm = 0; fm < 4; fm++)
#pragma unroll
      for (int rr = 0; rr < 4; rr++) {
        float v = acc[fm][fn][rr] + bz;
        acc[fm][fn][rr] = v;
        if (STATS) { s += v; q += v * v; }
      }
    if (STATS) {
      s += __shfl_xor(s, 16, 64); s += __shfl_xor(s, 32, 64);
      q += __shfl_xor(q, 16, 64); q += __shfl_xor(q, 32, 64);
      if (g == 0) {
        ps[(size_t)gcol * 1024 + blockIdx.x * 2 + wr] = s;
        pq[(size_t)gcol * 1024 + blockIdx.x * 2 + wr] = q;
      }
    }
  }

  if (F16OUT) {
    half_t* so = (half_t*)smem;  // [128][128]
#pragma unroll
    for (int fn = 0; fn < 4; fn++)
#pragma unroll
      for (int fm = 0; fm < 4; fm++)
#pragma unroll
        for (int rr = 0; rr < 4; rr++)
          so[(wr * 64 + fm * 16 + g * 4 + rr) * 128 + wc * 64 + fn * 16 + ml] =
              (half_t)acc[fm][fn][rr];
    __syncthreads();
#pragma unroll
    for (int it = 0; it < 8; it++) {
      int r = it * 16 + (tid >> 4);
      int c = (tid & 15) * 8;
      *(half8*)(o16 + (size_t)(brow + r) * ldo + bcol + c) = *(const half8*)&so[r * 128 + c];
    }
  } else {
    float* so = (float*)smem;    // [64][128]
    for (int h = 0; h < 2; h++) {
      if (wr == h) {
#pragma unroll
        for (int fn = 0; fn < 4; fn++)
#pragma unroll
          for (int fm = 0; fm < 4; fm++)
#pragma unroll
            for (int rr = 0; rr < 4; rr++)
              so[(fm * 16 + g * 4 + rr) * 128 + wc * 64 + fn * 16 + ml] = acc[fm][fn][rr];
      }
      __syncthreads();
      int r0 = h * 64;
      for (int i = tid; i < 64 * 64; i += 256) {
        int r  = i >> 6;
        int c2 = (i & 63) * 2;
        int gc = bcol + c2;
        if (gc < ncreal)
          *(float2*)(o32 + (size_t)(brow + r0 + r) * ldo + gc) = *(const float2*)&so[r * 128 + c2];
      }
      __syncthreads();
    }
  }
}

// ---------- BN finalize ----------
__global__ __launch_bounds__(256) void k_bnfinal(
    const float* __restrict__ ps, const float* __restrict__ pq,
    const float* __restrict__ gamma, const float* __restrict__ beta,
    float* __restrict__ sc, float* __restrict__ sh) {
  int c = blockIdx.x, t = threadIdx.x;
  float s = 0.f, q = 0.f;
#pragma unroll
  for (int i = 0; i < 4; i++) {
    s += ps[(size_t)c * 1024 + t + i * 256];
    q += pq[(size_t)c * 1024 + t + i * 256];
  }
#pragma unroll
  for (int o = 1; o < 64; o <<= 1) { s += __shfl_xor(s, o, 64); q += __shfl_xor(q, o, 64); }
  __shared__ float ss[4], qq[4];
  if ((t & 63) == 0) { ss[t >> 6] = s; qq[t >> 6] = q; }
  __syncthreads();
  if (t == 0) {
    s = ss[0] + ss[1] + ss[2] + ss[3];
    q = qq[0] + qq[1] + qq[2] + qq[3];
    float mu   = s * (1.f / NBATCH);
    float var  = fmaxf(q * (1.f / NBATCH) - mu * mu, 0.f);
    float rstd = rsqrtf(var + 1e-3f);
    float a = gamma[c] * rstd;
    sc[c] = a;
    sh[c] = beta[c] - mu * a;
  }
}

// ---------- in-place BN+ReLU on a 256-wide f16 slice of act ----------
__global__ __launch_bounds__(256) void k_bnrelu(half_t* __restrict__ p,
                                                const float* __restrict__ sc,
                                                const float* __restrict__ sh) {
  size_t i = (size_t)blockIdx.x * 256 + threadIdx.x;
  int row = (int)(i >> 5), c8 = (int)(i & 31) << 3;
  half_t* a = p + (size_t)row * 640 + c8;
  half8 v = *(const half8*)a;
  half8 o;
#pragma unroll
  for (int j = 0; j < 8; j++)
    o[j] = (half_t)fmaxf(fmaf((float)v[j], sc[c8 + j], sh[c8 + j]), 0.f);
  *(half8*)a = o;
}

// ---------- softmax helpers ----------
// full segment, runtime start, compile-time length
template<int L>
__device__ __forceinline__ void seg_rt(float* __restrict__ zr, int S) {
  float v[L];
#pragma unroll
  for (int j = 0; j < L; j++) v[j] = zr[S + j];
  float m0 = -1e30f, m1 = -1e30f, m2 = -1e30f, m3 = -1e30f;
#pragma unroll
  for (int j = 0; j < L; j++) {
    if ((j & 3) == 0) m0 = fmaxf(m0, v[j]);
    else if ((j & 3) == 1) m1 = fmaxf(m1, v[j]);
    else if ((j & 3) == 2) m2 = fmaxf(m2, v[j]);
    else m3 = fmaxf(m3, v[j]);
  }
  const float m = fmaxf(fmaxf(m0, m1), fmaxf(m2, m3));
  float s0 = 0.f, s1 = 0.f, s2 = 0.f, s3 = 0.f;
#pragma unroll
  for (int j = 0; j < L; j++) {
    float e = __expf(v[j] - m);
    v[j] = e;
    if ((j & 3) == 0) s0 += e;
    else if ((j & 3) == 1) s1 += e;
    else if ((j & 3) == 2) s2 += e;
    else s3 += e;
  }
  const float inv = 1.0f / ((s0 + s1) + (s2 + s3));
#pragma unroll
  for (int j = 0; j < L; j++) zr[S + j] = v[j] * inv;
}

// padded variant: shape L compile-time, real length Lr runtime (dummies = -inf,
// stores predicated). Lr==0 is benign (exp(0)=1 garbage confined to registers).
template<int L>
__device__ __forceinline__ void seg_pad(float* __restrict__ zr, int S, int Lr) {
  float v[L];
#pragma unroll
  for (int j = 0; j < L; j++) v[j] = (j < Lr) ? zr[S + j] : -1e30f;
  float m = -1e30f;
#pragma unroll
  for (int j = 0; j < L; j++) m = fmaxf(m, v[j]);
  float s = 0.f;
#pragma unroll
  for (int j = 0; j < L; j++) {
    float e = __expf(v[j] - m);
    v[j] = e;
    s += e;
  }
  const float inv = 1.0f / s;
#pragma unroll
  for (int j = 0; j < L; j++)
    if (j < Lr) zr[S + j] = v[j] * inv;
}

// segment split across a lane pair; combine with shfl_xor(.,1)
template<int S, int L>
__device__ __forceinline__ void seg_split(float* __restrict__ zr, int par) {
  constexpr int H = L / 2;
  const int base = S + par * H;
  float v[H];
#pragma unroll
  for (int j = 0; j < H; j++) v[j] = zr[base + j];
  float m = -1e30f;
#pragma unroll
  for (int j = 0; j < H; j++) m = fmaxf(m, v[j]);
  m = fmaxf(m, __shfl_xor(m, 1, 64));
  float s = 0.f;
#pragma unroll
  for (int j = 0; j < H; j++) {
    float e = __expf(v[j] - m);
    v[j] = e;
    s += e;
  }
  s += __shfl_xor(s, 1, 64);
  const float inv = 1.0f / s;
#pragma unroll
  for (int j = 0; j < H; j++) zr[base + j] = v[j] * inv;
}

// segment split across a lane QUAD; combine with shfl_xor 1 then 2.
// base/n per-lane (quad q handles [base, base+n)).
template<int H>
__device__ __forceinline__ void seg_quad(float* __restrict__ zr, int base, int n) {
  float v[H];
#pragma unroll
  for (int j = 0; j < H; j++) v[j] = (j < n) ? zr[base + j] : -1e30f;
  float m = -1e30f;
#pragma unroll
  for (int j = 0; j < H; j++) m = fmaxf(m, v[j]);
  m = fmaxf(m, __shfl_xor(m, 1, 64));
  m = fmaxf(m, __shfl_xor(m, 2, 64));
  float s = 0.f;
#pragma unroll
  for (int j = 0; j < H; j++) {
    float e = __expf(v[j] - m);
    v[j] = e;
    s += e;
  }
  s += __shfl_xor(s, 1, 64);
  s += __shfl_xor(s, 2, 64);
  const float inv = 1.0f / s;
#pragma unroll
  for (int j = 0; j < H; j++)
    if (j < n) zr[base + j] = v[j] * inv;
}

__device__ __forceinline__ bool is_alpha(int c) {
  const unsigned long long AM0 =
      (1ull << 0) | (1ull << 11) | (1ull << 20) | (1ull << 31) | (1ull << 37) |
      (1ull << 48) | (1ull << 59);
  const unsigned long long AM1 = (1ull << 3) | (1ull << 14) | (1ull << 25);  // 67,78,89
  if (c >= 90) return false;
  return (((c < 64) ? (AM0 >> c) : (AM1 >> (c - 64))) & 1ull) != 0ull;
}

// ---------- in-place gumbel-softmax: 32 rows/block ----------
// Big segs quad-split (4 lanes/row, waves own 16-row halves); rest pair-binned
// with uniform shapes (seg_rt/seg_pad) -> no intra-wave divergence, no extra
// barriers. Critical lane path ~26 elems (was 50).
__global__ __launch_bounds__(512, 2) void k_softmax(const float* __restrict__ g,
                                                    float* __restrict__ out) {
  __shared__ float zb[32][373];
  const int tid = threadIdx.x;
  const size_t gbase = (size_t)blockIdx.x * 32 * 366;
  for (int i2 = tid; i2 < 32 * 183; i2 += 512) {
    int e0 = i2 * 2;
    int r = e0 / 366;
    int c = e0 - r * 366;
    float2 lg = *(const float2*)(out + gbase + e0);
    float2 gg = *(const float2*)(g + gbase + e0);
    zb[r][c]     = is_alpha(c)     ? tanhf(lg.x) : (lg.x + gg.x) * 5.0f;
    zb[r][c + 1] = is_alpha(c + 1) ? tanhf(lg.y) : (lg.y + gg.y) * 5.0f;
  }
  __syncthreads();
  {
    const int lane = tid & 63;
    const int w    = tid >> 6;
    const int par  = lane & 1;
    if (w < 4) {
      // quad lanes per row; waves 0/2 rows 0-15, waves 1/3 rows 16-31
      const int quad = lane & 3;
      float* zr = &zb[(w & 1) * 16 + (lane >> 2)][0];
      if (w < 2) {
        seg_quad<25>(zr, 184 + quad * 25, 25);                       // seg(184,100)
      } else {
        // seg(120,50): quads take 13,13,12,12
        seg_quad<13>(zr, 120 + quad * 13 - (quad >> 1) * (quad & 1), 13 - (quad >> 1));
        // duplicated across quad-pairs (benign identical writes)
        seg_rt<10>(zr, par ? 68 : 1);
      }
    } else {
      float* zr = &zb[lane >> 1][0];
      switch (w) {
        case 4: seg_split<314, 30>(zr, par);
                seg_rt<7>(zr, par ? 359 : 60);
                seg_rt<2>(zr, par ? 174 : 100);
                seg_rt<2>(zr, par ? 312 : 290); break;
        case 5: seg_rt<10>(zr, par ? 90 : 38);
                seg_rt<10>(zr, par ? 107 : 49);
                seg_pad<2>(zr, par ? 357 : 0, par ? 2 : 0); break;
        case 6: seg_pad<12>(zr, par ? 348 : 295, par ? 9 : 12);
                seg_pad<6>(zr, par ? 284 : 32, par ? 6 : 5);
                seg_rt<5>(zr, par ? 307 : 102); break;
        default: seg_rt<10>(zr, par ? 79 : 21);
                 seg_rt<8>(zr, par ? 176 : 12);
                 seg_rt<4>(zr, par ? 344 : 170);
                 seg_rt<3>(zr, par ? 292 : 117); break;
      }
    }
  }
  __syncthreads();
  for (int i2 = tid; i2 < 32 * 183; i2 += 512) {
    int e0 = i2 * 2;
    int r = e0 / 366;
    int c = e0 - r * 366;
    float2 o;
    o.x = zb[r][c];
    o.y = zb[r][c + 1];
    *(float2*)(out + gbase + e0) = o;
  }
}

extern "C" void kernel_launch(void* const* d_in, const int* in_sizes, int n_in,
                              void* d_out, int out_size, void* d_ws, size_t ws_size,
                              hipStream_t stream) {
  const float* z      = (const float*)d_in[0];
  const float* g      = (const float*)d_in[1];
  const float* W1     = (const float*)d_in[2];
  const float* b1     = (const float*)d_in[3];
  const float* gamma1 = (const float*)d_in[4];
  const float* beta1  = (const float*)d_in[5];
  const float* W2     = (const float*)d_in[6];
  const float* b2     = (const float*)d_in[7];
  const float* gamma2 = (const float*)d_in[8];
  const float* beta2  = (const float*)d_in[9];
  const float* Wout   = (const float*)d_in[10];
  const float* bout   = (const float*)d_in[11];
  float* out = (float*)d_out;
  char* ws = (char*)d_ws;

  size_t off = 0;
  half_t* act = (half_t*)(ws + off); off += (size_t)NBATCH * 640 * 2;  // [B][p2|p1|z]
  half_t* W1t = (half_t*)(ws + off); off += (size_t)256 * 128 * 2;
  half_t* W2t = (half_t*)(ws + off); off += (size_t)256 * 384 * 2;
  half_t* Wot = (half_t*)(ws + off); off += (size_t)384 * 640 * 2;
  float*  ps  = (float*)(ws + off);  off += (size_t)256 * 1024 * 4;
  float*  pq  = (float*)(ws + off);  off += (size_t)256 * 1024 * 4;
  float*  sc1 = (float*)(ws + off);  off += 256 * 4;
  float*  sh1 = (float*)(ws + off);  off += 256 * 4;
  float*  sc2 = (float*)(ws + off);  off += 256 * 4;
  float*  sh2 = (float*)(ws + off);  off += 256 * 4;
  (void)ws_size; (void)in_sizes; (void)n_in; (void)out_size;

  // prep: z into act cols 512..639, transposed f16 weights
  k_cvtz<<<4096, 256, 0, stream>>>(z, act + 512);
  k_transpose<<<(256 * 128 + 255) / 256, 256, 0, stream>>>(W1, W1t, 128, 256, 256 * 128);
  k_transpose<<<(256 * 384 + 255) / 256, 256, 0, stream>>>(W2, W2t, 384, 256, 256 * 384);
  k_transpose<<<(384 * 640 + 255) / 256, 256, 0, stream>>>(Wout, Wot, 640, 366, 384 * 640);

  // layer 1: h1(f16, act cols 256..511) = z @ W1 + b1, fused stats
  k_gemm<true, true><<<dim3(512, 2), 256, 0, stream>>>(
      act + 512, 640, 128, W1t, b1, act + 256, nullptr, 640, 256, ps, pq);
  k_bnfinal<<<256, 256, 0, stream>>>(ps, pq, gamma1, beta1, sc1, sh1);
  k_bnrelu<<<8192, 256, 0, stream>>>(act + 256, sc1, sh1);

  // layer 2: h2(f16, act cols 0..255) = [p1|z] @ W2 + b2, fused stats
  k_gemm<true, true><<<dim3(512, 2), 256, 0, stream>>>(
      act + 256, 640, 384, W2t, b2, act + 0, nullptr, 640, 256, ps, pq);
  k_bnfinal<<<256, 256, 0, stream>>>(ps, pq, gamma2, beta2, sc2, sh2);
  k_bnrelu<<<8192, 256, 0, stream>>>(act + 0, sc2, sh2);

  // output layer: logits(f32, dense) = [p2|p1|z] @ Wout + bout -> d_out
  k_gemm<false, false><<<dim3(512, 3), 256, 0, stream>>>(
      act, 640, 640, Wot, bout, nullptr, out, 366, 366, nullptr, nullptr);

  // in-place ragged gumbel-softmax + tanh
  k_softmax<<<NBATCH / 32, 512, 0, stream>>>(g, out);
}

// Round 9
// 207.052 us; speedup vs baseline: 1.8939x; 1.0387x over previous
//
#include <hip/hip_runtime.h>

typedef _Float16 half_t;
typedef _Float16 half4 __attribute__((ext_vector_type(4)));
typedef _Float16 half8 __attribute__((ext_vector_type(8)));
typedef float f32x4 __attribute__((ext_vector_type(4)));

#define AS1 __attribute__((address_space(1)))
#define AS3 __attribute__((address_space(3)))

static constexpr int NBATCH = 65536;

// ---------- z f32 -> f16 into act[:,512:640] ----------
__global__ __launch_bounds__(256) void k_cvtz(const float* __restrict__ z,
                                              half_t* __restrict__ dst) {
  size_t i = (size_t)blockIdx.x * 256 + threadIdx.x;
  int row = (int)(i >> 4), c8 = (int)(i & 15) << 3;
  const float* s = z + (size_t)row * 128 + c8;
  float4 v0 = *(const float4*)s;
  float4 v1 = *(const float4*)(s + 4);
  half8 h;
  h[0]=(half_t)v0.x; h[1]=(half_t)v0.y; h[2]=(half_t)v0.z; h[3]=(half_t)v0.w;
  h[4]=(half_t)v1.x; h[5]=(half_t)v1.y; h[6]=(half_t)v1.z; h[7]=(half_t)v1.w;
  *(half8*)(dst + (size_t)row * 640 + c8) = h;
}

// ---------- W [K][N] f32 -> Wt [Npad][K] f16 (zero-pad n >= N) ----------
__global__ __launch_bounds__(256) void k_transpose(const float* __restrict__ W,
                                                   half_t* __restrict__ Wt,
                                                   int K, int N, int total) {
  int i = blockIdx.x * 256 + threadIdx.x;
  if (i >= total) return;
  int n = i / K;
  int k = i - n * K;
  float v = (n < N) ? W[k * N + n] : 0.f;
  Wt[i] = (half_t)v;
}

// ---------- GEMM: 128x128 tile, BK=64, 2-phase dbuf pipeline, x32 MFMA ----------
// LDS layout per buffer: A [128 rows][8 chunks of 16B], chunk c of row r stored
// at slot c^(r&7); staged by global_load_lds with pre-swizzled global source.
// Fragment read: one ds_read_b128 per 16x16x32 MFMA operand (conflict-free).
template<bool STATS, bool F16OUT>
__global__ __launch_bounds__(256) void k_gemm(
    const half_t* __restrict__ A, int lda, int K,
    const half_t* __restrict__ Bt,
    const float* __restrict__ bias,
    half_t* __restrict__ o16, float* __restrict__ o32, int ldo, int ncreal,
    float* __restrict__ ps, float* __restrict__ pq) {
  __shared__ __align__(16) char smem[65536];   // 2 x (A 16K + B 16K)
  const int tid  = threadIdx.x;
  const int lane = tid & 63;
  const int w    = tid >> 6;
  const int wr   = w >> 1, wc = w & 1;
  const int ml   = lane & 15, g = lane >> 4;
  const int brow = blockIdx.x * 128;
  const int bcol = blockIdx.y * 128;
  const int sr  = lane >> 3;
  const int scg = (lane & 7) ^ sr;

  f32x4 acc[4][4];
#pragma unroll
  for (int i = 0; i < 4; i++)
#pragma unroll
    for (int j = 0; j < 4; j++) acc[i][j] = (f32x4){0.f, 0.f, 0.f, 0.f};

  const half_t* Abase = A  + (size_t)brow * lda;
  const half_t* Bbase = Bt + (size_t)bcol * K;
  const int nt = K >> 6;

  auto stage = [&](int t, int p) {
    half_t* As = (half_t*)(smem + p * 32768);
    half_t* Bs = (half_t*)(smem + p * 32768 + 16384);
    const int k0 = t * 64;
#pragma unroll
    for (int it = 0; it < 4; it++) {
      int q = it * 4 + w;                 // 0..15, rows q*8..q*8+7
      int r = q * 8 + sr;
      __builtin_amdgcn_global_load_lds(
          (AS1 const void*)(Abase + (size_t)r * lda + k0 + scg * 8),
          (AS3 void*)(As + q * 512), 16, 0, 0);
      __builtin_amdgcn_global_load_lds(
          (AS1 const void*)(Bbase + (size_t)r * K + k0 + scg * 8),
          (AS3 void*)(Bs + q * 512), 16, 0, 0);
    }
  };
  auto compute = [&](int p) {
    const char* As = (const char*)smem + p * 32768;
    const char* Bs = (const char*)smem + p * 32768 + 16384;
#pragma unroll
    for (int t2 = 0; t2 < 2; t2++) {      // two K=32 blocks per tile
      const int c4 = t2 * 4 + g;
      half8 af[4], bf[4];
#pragma unroll
      for (int fm = 0; fm < 4; fm++) {
        int row = wr * 64 + fm * 16 + ml;
        af[fm] = *(const half8*)(As + row * 128 + ((c4 ^ (row & 7)) << 4));
      }
#pragma unroll
      for (int fn = 0; fn < 4; fn++) {
        int row = wc * 64 + fn * 16 + ml;
        bf[fn] = *(const half8*)(Bs + row * 128 + ((c4 ^ (row & 7)) << 4));
      }
#pragma unroll
      for (int fm = 0; fm < 4; fm++)
#pragma unroll
        for (int fn = 0; fn < 4; fn++)
          acc[fm][fn] = __builtin_amdgcn_mfma_f32_16x16x32_f16(af[fm], bf[fn], acc[fm][fn], 0, 0, 0);
    }
  };

  // pipelined K-loop: stage t+1 before computing t; counted vmcnt keeps the
  // next tile's 8 loads in flight across the barrier (no full drain).
  stage(0, 0);
  int p = 0;
  for (int t = 0; t < nt - 1; t++) {
    stage(t + 1, p ^ 1);
    asm volatile("s_waitcnt vmcnt(8)\ns_barrier" ::: "memory");
    compute(p);
    asm volatile("s_barrier" ::: "memory");
    p ^= 1;
  }
  asm volatile("s_waitcnt vmcnt(0)\ns_barrier" ::: "memory");
  compute(p);
  __syncthreads();

  // bias + optional stats (C/D layout: col = lane&15, row = 4*(lane>>4)+reg)
#pragma unroll
  for (int fn = 0; fn < 4; fn++) {
    int col  = wc * 64 + fn * 16 + ml;
    int gcol = bcol + col;
    float bz = (gcol < ncreal) ? bias[gcol] : 0.f;
    float s = 0.f, q = 0.f;
#pragma unroll
    for (int fm = 0; fm < 4; fm++)
#pragma unroll
      for (int rr = 0; rr < 4; rr++) {
        float v = acc[fm][fn][rr] + bz;
        acc[fm][fn][rr] = v;
        if (STATS) { s += v; q += v * v; }
      }
    if (STATS) {
      s += __shfl_xor(s, 16, 64); s += __shfl_xor(s, 32, 64);
      q += __shfl_xor(q, 16, 64); q += __shfl_xor(q, 32, 64);
      if (g == 0) {
        ps[(size_t)gcol * 1024 + blockIdx.x * 2 + wr] = s;
        pq[(size_t)gcol * 1024 + blockIdx.x * 2 + wr] = q;
      }
    }
  }

  if (F16OUT) {
    half_t* so = (half_t*)smem;  // [128][128]
#pragma unroll
    for (int fn = 0; fn < 4; fn++)
#pragma unroll
      for (int fm = 0; fm < 4; fm++)
#pragma unroll
        for (int rr = 0; rr < 4; rr++)
          so[(wr * 64 + fm * 16 + g * 4 + rr) * 128 + wc * 64 + fn * 16 + ml] =
              (half_t)acc[fm][fn][rr];
    __syncthreads();
#pragma unroll
    for (int it = 0; it < 8; it++) {
      int r = it * 16 + (tid >> 4);
      int c = (tid & 15) * 8;
      *(half8*)(o16 + (size_t)(brow + r) * ldo + bcol + c) = *(const half8*)&so[r * 128 + c];
    }
  } else {
    float* so = (float*)smem;    // [64][128]
    for (int h = 0; h < 2; h++) {
      if (wr == h) {
#pragma unroll
        for (int fn = 0; fn < 4; fn++)
#pragma unroll
          for (int fm = 0; fm < 4; fm++)
#pragma unroll
            for (int rr = 0; rr < 4; rr++)
              so[(fm * 16 + g * 4 + rr) * 128 + wc * 64 + fn * 16 + ml] = acc[fm][fn][rr];
      }
      __syncthreads();
      int r0 = h * 64;
      for (int i = tid; i < 64 * 64; i += 256) {
        int r  = i >> 6;
        int c2 = (i & 63) * 2;
        int gc = bcol + c2;
        if (gc < ncreal)
          *(float2*)(o32 + (size_t)(brow + r0 + r) * ldo + gc) = *(const float2*)&so[r * 128 + c2];
      }
      __syncthreads();
    }
  }
}

// ---------- BN finalize ----------
__global__ __launch_bounds__(256) void k_bnfinal(
    const float* __restrict__ ps, const float* __restrict__ pq,
    const float* __restrict__ gamma, const float* __restrict__ beta,
    float* __restrict__ sc, float* __restrict__ sh) {
  int c = blockIdx.x, t = threadIdx.x;
  float s = 0.f, q = 0.f;
#pragma unroll
  for (int i = 0; i < 4; i++) {
    s += ps[(size_t)c * 1024 + t + i * 256];
    q += pq[(size_t)c * 1024 + t + i * 256];
  }
#pragma unroll
  for (int o = 1; o < 64; o <<= 1) { s += __shfl_xor(s, o, 64); q += __shfl_xor(q, o, 64); }
  __shared__ float ss[4], qq[4];
  if ((t & 63) == 0) { ss[t >> 6] = s; qq[t >> 6] = q; }
  __syncthreads();
  if (t == 0) {
    s = ss[0] + ss[1] + ss[2] + ss[3];
    q = qq[0] + qq[1] + qq[2] + qq[3];
    float mu   = s * (1.f / NBATCH);
    float var  = fmaxf(q * (1.f / NBATCH) - mu * mu, 0.f);
    float rstd = rsqrtf(var + 1e-3f);
    float a = gamma[c] * rstd;
    sc[c] = a;
    sh[c] = beta[c] - mu * a;
  }
}

// ---------- in-place BN+ReLU on a 256-wide f16 slice of act ----------
__global__ __launch_bounds__(256) void k_bnrelu(half_t* __restrict__ p,
                                                const float* __restrict__ sc,
                                                const float* __restrict__ sh) {
  size_t i = (size_t)blockIdx.x * 256 + threadIdx.x;
  int row = (int)(i >> 5), c8 = (int)(i & 31) << 3;
  half_t* a = p + (size_t)row * 640 + c8;
  half8 v = *(const half8*)a;
  half8 o;
#pragma unroll
  for (int j = 0; j < 8; j++)
    o[j] = (half_t)fmaxf(fmaf((float)v[j], sc[c8 + j], sh[c8 + j]), 0.f);
  *(half8*)a = o;
}

// ---------- softmax helpers ----------
template<int L>
__device__ __forceinline__ void seg_rt(float* __restrict__ zr, int S) {
  float v[L];
#pragma unroll
  for (int j = 0; j < L; j++) v[j] = zr[S + j];
  float m0 = -1e30f, m1 = -1e30f, m2 = -1e30f, m3 = -1e30f;
#pragma unroll
  for (int j = 0; j < L; j++) {
    if ((j & 3) == 0) m0 = fmaxf(m0, v[j]);
    else if ((j & 3) == 1) m1 = fmaxf(m1, v[j]);
    else if ((j & 3) == 2) m2 = fmaxf(m2, v[j]);
    else m3 = fmaxf(m3, v[j]);
  }
  const float m = fmaxf(fmaxf(m0, m1), fmaxf(m2, m3));
  float s0 = 0.f, s1 = 0.f, s2 = 0.f, s3 = 0.f;
#pragma unroll
  for (int j = 0; j < L; j++) {
    float e = __expf(v[j] - m);
    v[j] = e;
    if ((j & 3) == 0) s0 += e;
    else if ((j & 3) == 1) s1 += e;
    else if ((j & 3) == 2) s2 += e;
    else s3 += e;
  }
  const float inv = 1.0f / ((s0 + s1) + (s2 + s3));
#pragma unroll
  for (int j = 0; j < L; j++) zr[S + j] = v[j] * inv;
}

template<int L>
__device__ __forceinline__ void seg_pad(float* __restrict__ zr, int S, int Lr) {
  float v[L];
#pragma unroll
  for (int j = 0; j < L; j++) v[j] = (j < Lr) ? zr[S + j] : -1e30f;
  float m = -1e30f;
#pragma unroll
  for (int j = 0; j < L; j++) m = fmaxf(m, v[j]);
  float s = 0.f;
#pragma unroll
  for (int j = 0; j < L; j++) {
    float e = __expf(v[j] - m);
    v[j] = e;
    s += e;
  }
  const float inv = 1.0f / s;
#pragma unroll
  for (int j = 0; j < L; j++)
    if (j < Lr) zr[S + j] = v[j] * inv;
}

template<int S, int L>
__device__ __forceinline__ void seg_split(float* __restrict__ zr, int par) {
  constexpr int H = L / 2;
  const int base = S + par * H;
  float v[H];
#pragma unroll
  for (int j = 0; j < H; j++) v[j] = zr[base + j];
  float m = -1e30f;
#pragma unroll
  for (int j = 0; j < H; j++) m = fmaxf(m, v[j]);
  m = fmaxf(m, __shfl_xor(m, 1, 64));
  float s = 0.f;
#pragma unroll
  for (int j = 0; j < H; j++) {
    float e = __expf(v[j] - m);
    v[j] = e;
    s += e;
  }
  s += __shfl_xor(s, 1, 64);
  const float inv = 1.0f / s;
#pragma unroll
  for (int j = 0; j < H; j++) zr[base + j] = v[j] * inv;
}

template<int H>
__device__ __forceinline__ void seg_quad(float* __restrict__ zr, int base, int n) {
  float v[H];
#pragma unroll
  for (int j = 0; j < H; j++) v[j] = (j < n) ? zr[base + j] : -1e30f;
  float m = -1e30f;
#pragma unroll
  for (int j = 0; j < H; j++) m = fmaxf(m, v[j]);
  m = fmaxf(m, __shfl_xor(m, 1, 64));
  m = fmaxf(m, __shfl_xor(m, 2, 64));
  float s = 0.f;
#pragma unroll
  for (int j = 0; j < H; j++) {
    float e = __expf(v[j] - m);
    v[j] = e;
    s += e;
  }
  s += __shfl_xor(s, 1, 64);
  s += __shfl_xor(s, 2, 64);
  const float inv = 1.0f / s;
#pragma unroll
  for (int j = 0; j < H; j++)
    if (j < n) zr[base + j] = v[j] * inv;
}

__device__ __forceinline__ bool is_alpha(int c) {
  const unsigned long long AM0 =
      (1ull << 0) | (1ull << 11) | (1ull << 20) | (1ull << 31) | (1ull << 37) |
      (1ull << 48) | (1ull << 59);
  const unsigned long long AM1 = (1ull << 3) | (1ull << 14) | (1ull << 25);  // 67,78,89
  if (c >= 90) return false;
  return (((c < 64) ? (AM0 >> c) : (AM1 >> (c - 64))) & 1ull) != 0ull;
}

// ---------- in-place gumbel-softmax: 32 rows/block ----------
__global__ __launch_bounds__(512, 2) void k_softmax(const float* __restrict__ g,
                                                    float* __restrict__ out) {
  __shared__ float zb[32][373];
  const int tid = threadIdx.x;
  const size_t gbase = (size_t)blockIdx.x * 32 * 366;
  for (int i2 = tid; i2 < 32 * 183; i2 += 512) {
    int e0 = i2 * 2;
    int r = e0 / 366;
    int c = e0 - r * 366;
    float2 lg = *(const float2*)(out + gbase + e0);
    float2 gg = *(const float2*)(g + gbase + e0);
    zb[r][c]     = is_alpha(c)     ? tanhf(lg.x) : (lg.x + gg.x) * 5.0f;
    zb[r][c + 1] = is_alpha(c + 1) ? tanhf(lg.y) : (lg.y + gg.y) * 5.0f;
  }
  __syncthreads();
  {
    const int lane = tid & 63;
    const int w    = tid >> 6;
    const int par  = lane & 1;
    if (w < 4) {
      const int quad = lane & 3;
      float* zr = &zb[(w & 1) * 16 + (lane >> 2)][0];
      if (w < 2) {
        seg_quad<25>(zr, 184 + quad * 25, 25);                       // seg(184,100)
      } else {
        seg_quad<13>(zr, 120 + quad * 13 - (quad >> 1) * (quad & 1), 13 - (quad >> 1));
        seg_rt<10>(zr, par ? 68 : 1);
      }
    } else {
      float* zr = &zb[lane >> 1][0];
      switch (w) {
        case 4: seg_split<314, 30>(zr, par);
                seg_rt<7>(zr, par ? 359 : 60);
                seg_rt<2>(zr, par ? 174 : 100);
                seg_rt<2>(zr, par ? 312 : 290); break;
        case 5: seg_rt<10>(zr, par ? 90 : 38);
                seg_rt<10>(zr, par ? 107 : 49);
                seg_pad<2>(zr, par ? 357 : 0, par ? 2 : 0); break;
        case 6: seg_pad<12>(zr, par ? 348 : 295, par ? 9 : 12);
                seg_pad<6>(zr, par ? 284 : 32, par ? 6 : 5);
                seg_rt<5>(zr, par ? 307 : 102); break;
        default: seg_rt<10>(zr, par ? 79 : 21);
                 seg_rt<8>(zr, par ? 176 : 12);
                 seg_rt<4>(zr, par ? 344 : 170);
                 seg_rt<3>(zr, par ? 292 : 117); break;
      }
    }
  }
  __syncthreads();
  for (int i2 = tid; i2 < 32 * 183; i2 += 512) {
    int e0 = i2 * 2;
    int r = e0 / 366;
    int c = e0 - r * 366;
    float2 o;
    o.x = zb[r][c];
    o.y = zb[r][c + 1];
    *(float2*)(out + gbase + e0) = o;
  }
}

extern "C" void kernel_launch(void* const* d_in, const int* in_sizes, int n_in,
                              void* d_out, int out_size, void* d_ws, size_t ws_size,
                              hipStream_t stream) {
  const float* z      = (const float*)d_in[0];
  const float* g      = (const float*)d_in[1];
  const float* W1     = (const float*)d_in[2];
  const float* b1     = (const float*)d_in[3];
  const float* gamma1 = (const float*)d_in[4];
  const float* beta1  = (const float*)d_in[5];
  const float* W2     = (const float*)d_in[6];
  const float* b2     = (const float*)d_in[7];
  const float* gamma2 = (const float*)d_in[8];
  const float* beta2  = (const float*)d_in[9];
  const float* Wout   = (const float*)d_in[10];
  const float* bout   = (const float*)d_in[11];
  float* out = (float*)d_out;
  char* ws = (char*)d_ws;

  size_t off = 0;
  half_t* act = (half_t*)(ws + off); off += (size_t)NBATCH * 640 * 2;  // [B][p2|p1|z]
  half_t* W1t = (half_t*)(ws + off); off += (size_t)256 * 128 * 2;
  half_t* W2t = (half_t*)(ws + off); off += (size_t)256 * 384 * 2;
  half_t* Wot = (half_t*)(ws + off); off += (size_t)384 * 640 * 2;
  float*  ps  = (float*)(ws + off);  off += (size_t)256 * 1024 * 4;
  float*  pq  = (float*)(ws + off);  off += (size_t)256 * 1024 * 4;
  float*  sc1 = (float*)(ws + off);  off += 256 * 4;
  float*  sh1 = (float*)(ws + off);  off += 256 * 4;
  float*  sc2 = (float*)(ws + off);  off += 256 * 4;
  float*  sh2 = (float*)(ws + off);  off += 256 * 4;
  (void)ws_size; (void)in_sizes; (void)n_in; (void)out_size;

  // prep: z into act cols 512..639, transposed f16 weights
  k_cvtz<<<4096, 256, 0, stream>>>(z, act + 512);
  k_transpose<<<(256 * 128 + 255) / 256, 256, 0, stream>>>(W1, W1t, 128, 256, 256 * 128);
  k_transpose<<<(256 * 384 + 255) / 256, 256, 0, stream>>>(W2, W2t, 384, 256, 256 * 384);
  k_transpose<<<(384 * 640 + 255) / 256, 256, 0, stream>>>(Wout, Wot, 640, 366, 384 * 640);

  // layer 1: h1(f16, act cols 256..511) = z @ W1 + b1, fused stats
  k_gemm<true, true><<<dim3(512, 2), 256, 0, stream>>>(
      act + 512, 640, 128, W1t, b1, act + 256, nullptr, 640, 256, ps, pq);
  k_bnfinal<<<256, 256, 0, stream>>>(ps, pq, gamma1, beta1, sc1, sh1);
  k_bnrelu<<<8192, 256, 0, stream>>>(act + 256, sc1, sh1);

  // layer 2: h2(f16, act cols 0..255) = [p1|z] @ W2 + b2, fused stats
  k_gemm<true, true><<<dim3(512, 2), 256, 0, stream>>>(
      act + 256, 640, 384, W2t, b2, act + 0, nullptr, 640, 256, ps, pq);
  k_bnfinal<<<256, 256, 0, stream>>>(ps, pq, gamma2, beta2, sc2, sh2);
  k_bnrelu<<<8192, 256, 0, stream>>>(act + 0, sc2, sh2);

  // output layer: logits(f32, dense) = [p2|p1|z] @ Wout + bout -> d_out
  k_gemm<false, false><<<dim3(512, 3), 256, 0, stream>>>(
      act, 640, 640, Wot, bout, nullptr, out, 366, 366, nullptr, nullptr);

  // in-place ragged gumbel-softmax + tanh
  k_softmax<<<NBATCH / 32, 512, 0, stream>>>(g, out);
}

// Round 10
// 199.415 us; speedup vs baseline: 1.9664x; 1.0383x over previous
//
#include <hip/hip_runtime.h>

typedef _Float16 half_t;
typedef _Float16 half4 __attribute__((ext_vector_type(4)));
typedef _Float16 half8 __attribute__((ext_vector_type(8)));
typedef float f32x4 __attribute__((ext_vector_type(4)));

#define AS1 __attribute__((address_space(1)))
#define AS3 __attribute__((address_space(3)))

static constexpr int NBATCH = 65536;

// ---------- z f32 -> f16 into act[:,512:640] ----------
__global__ __launch_bounds__(256) void k_cvtz(const float* __restrict__ z,
                                              half_t* __restrict__ dst) {
  size_t i = (size_t)blockIdx.x * 256 + threadIdx.x;
  int row = (int)(i >> 4), c8 = (int)(i & 15) << 3;
  const float* s = z + (size_t)row * 128 + c8;
  float4 v0 = *(const float4*)s;
  float4 v1 = *(const float4*)(s + 4);
  half8 h;
  h[0]=(half_t)v0.x; h[1]=(half_t)v0.y; h[2]=(half_t)v0.z; h[3]=(half_t)v0.w;
  h[4]=(half_t)v1.x; h[5]=(half_t)v1.y; h[6]=(half_t)v1.z; h[7]=(half_t)v1.w;
  *(half8*)(dst + (size_t)row * 640 + c8) = h;
}

// ---------- W [K][N] f32 -> Wt [Npad][K] f16 (zero-pad n >= N) ----------
__global__ __launch_bounds__(256) void k_transpose(const float* __restrict__ W,
                                                   half_t* __restrict__ Wt,
                                                   int K, int N, int total) {
  int i = blockIdx.x * 256 + threadIdx.x;
  if (i >= total) return;
  int n = i / K;
  int k = i - n * K;
  float v = (n < N) ? W[k * N + n] : 0.f;
  Wt[i] = (half_t)v;
}

// ---------- GEMM: 128x128 tile, BK=64, single-buffer (m97 structure), x32 MFMA ----------
// LDS: A [128 rows][8 chunks of 16B], chunk c of row r at slot c^(r&7); staged by
// global_load_lds with pre-swizzled global source. Full-drain barrier per tile;
// 32KB LDS -> ~4-5 blocks/CU so cross-block wave overlap hides the drain (m114).
// Fragment read: one ds_read_b128 per 16x16x32 MFMA operand (conflict-free).
template<bool STATS, bool F16OUT>
__global__ __launch_bounds__(256) void k_gemm(
    const half_t* __restrict__ A, int lda, int K,
    const half_t* __restrict__ Bt,
    const float* __restrict__ bias,
    half_t* __restrict__ o16, float* __restrict__ o32, int ldo, int ncreal,
    float* __restrict__ ps, float* __restrict__ pq) {
  __shared__ __align__(16) char smem[32768];   // A 16K + B 16K
  const int tid  = threadIdx.x;
  const int lane = tid & 63;
  const int w    = tid >> 6;
  const int wr   = w >> 1, wc = w & 1;
  const int ml   = lane & 15, g = lane >> 4;
  const int brow = blockIdx.x * 128;
  const int bcol = blockIdx.y * 128;
  const int sr  = lane >> 3;
  const int scg = (lane & 7) ^ sr;

  f32x4 acc[4][4];
#pragma unroll
  for (int i = 0; i < 4; i++)
#pragma unroll
    for (int j = 0; j < 4; j++) acc[i][j] = (f32x4){0.f, 0.f, 0.f, 0.f};

  const half_t* Abase = A  + (size_t)brow * lda;
  const half_t* Bbase = Bt + (size_t)bcol * K;
  const int nt = K >> 6;

  half_t* As = (half_t*)smem;
  half_t* Bs = (half_t*)(smem + 16384);

  for (int t = 0; t < nt; t++) {
    const int k0 = t * 64;
    if (t) __syncthreads();              // protect LDS from overwrite
#pragma unroll
    for (int it = 0; it < 4; it++) {
      int q = it * 4 + w;                // 0..15, rows q*8..q*8+7
      int r = q * 8 + sr;
      __builtin_amdgcn_global_load_lds(
          (AS1 const void*)(Abase + (size_t)r * lda + k0 + scg * 8),
          (AS3 void*)(As + q * 512), 16, 0, 0);
      __builtin_amdgcn_global_load_lds(
          (AS1 const void*)(Bbase + (size_t)r * K + k0 + scg * 8),
          (AS3 void*)(Bs + q * 512), 16, 0, 0);
    }
    __syncthreads();                     // drains vmcnt -> tile visible
#pragma unroll
    for (int t2 = 0; t2 < 2; t2++) {     // two K=32 blocks per tile
      const int c4 = t2 * 4 + g;
      half8 af[4], bf[4];
#pragma unroll
      for (int fm = 0; fm < 4; fm++) {
        int row = wr * 64 + fm * 16 + ml;
        af[fm] = *(const half8*)((const char*)As + row * 128 + ((c4 ^ (row & 7)) << 4));
      }
#pragma unroll
      for (int fn = 0; fn < 4; fn++) {
        int row = wc * 64 + fn * 16 + ml;
        bf[fn] = *(const half8*)((const char*)Bs + row * 128 + ((c4 ^ (row & 7)) << 4));
      }
#pragma unroll
      for (int fm = 0; fm < 4; fm++)
#pragma unroll
        for (int fn = 0; fn < 4; fn++)
          acc[fm][fn] = __builtin_amdgcn_mfma_f32_16x16x32_f16(af[fm], bf[fn], acc[fm][fn], 0, 0, 0);
    }
  }
  __syncthreads();

  // bias + optional stats (C/D layout: col = lane&15, row = 4*(lane>>4)+reg)
#pragma unroll
  for (int fn = 0; fn < 4; fn++) {
    int col  = wc * 64 + fn * 16 + ml;
    int gcol = bcol + col;
    float bz = (gcol < ncreal) ? bias[gcol] : 0.f;
    float s = 0.f, q = 0.f;
#pragma unroll
    for (int fm = 0; fm < 4; fm++)
#pragma unroll
      for (int rr = 0; rr < 4; rr++) {
        float v = acc[fm][fn][rr] + bz;
        acc[fm][fn][rr] = v;
        if (STATS) { s += v; q += v * v; }
      }
    if (STATS) {
      s += __shfl_xor(s, 16, 64); s += __shfl_xor(s, 32, 64);
      q += __shfl_xor(q, 16, 64); q += __shfl_xor(q, 32, 64);
      if (g == 0) {
        ps[(size_t)gcol * 1024 + blockIdx.x * 2 + wr] = s;
        pq[(size_t)gcol * 1024 + blockIdx.x * 2 + wr] = q;
      }
    }
  }

  if (F16OUT) {
    half_t* so = (half_t*)smem;  // [128][128]
#pragma unroll
    for (int fn = 0; fn < 4; fn++)
#pragma unroll
      for (int fm = 0; fm < 4; fm++)
#pragma unroll
        for (int rr = 0; rr < 4; rr++)
          so[(wr * 64 + fm * 16 + g * 4 + rr) * 128 + wc * 64 + fn * 16 + ml] =
              (half_t)acc[fm][fn][rr];
    __syncthreads();
#pragma unroll
    for (int it = 0; it < 8; it++) {
      int r = it * 16 + (tid >> 4);
      int c = (tid & 15) * 8;
      *(half8*)(o16 + (size_t)(brow + r) * ldo + bcol + c) = *(const half8*)&so[r * 128 + c];
    }
  } else {
    float* so = (float*)smem;    // [64][128]
    for (int h = 0; h < 2; h++) {
      if (wr == h) {
#pragma unroll
        for (int fn = 0; fn < 4; fn++)
#pragma unroll
          for (int fm = 0; fm < 4; fm++)
#pragma unroll
            for (int rr = 0; rr < 4; rr++)
              so[(fm * 16 + g * 4 + rr) * 128 + wc * 64 + fn * 16 + ml] = acc[fm][fn][rr];
      }
      __syncthreads();
      int r0 = h * 64;
      for (int i = tid; i < 64 * 64; i += 256) {
        int r  = i >> 6;
        int c2 = (i & 63) * 2;
        int gc = bcol + c2;
        if (gc < ncreal)
          *(float2*)(o32 + (size_t)(brow + r0 + r) * ldo + gc) = *(const float2*)&so[r * 128 + c2];
      }
      __syncthreads();
    }
  }
}

// ---------- BN finalize ----------
__global__ __launch_bounds__(256) void k_bnfinal(
    const float* __restrict__ ps, const float* __restrict__ pq,
    const float* __restrict__ gamma, const float* __restrict__ beta,
    float* __restrict__ sc, float* __restrict__ sh) {
  int c = blockIdx.x, t = threadIdx.x;
  float s = 0.f, q = 0.f;
#pragma unroll
  for (int i = 0; i < 4; i++) {
    s += ps[(size_t)c * 1024 + t + i * 256];
    q += pq[(size_t)c * 1024 + t + i * 256];
  }
#pragma unroll
  for (int o = 1; o < 64; o <<= 1) { s += __shfl_xor(s, o, 64); q += __shfl_xor(q, o, 64); }
  __shared__ float ss[4], qq[4];
  if ((t & 63) == 0) { ss[t >> 6] = s; qq[t >> 6] = q; }
  __syncthreads();
  if (t == 0) {
    s = ss[0] + ss[1] + ss[2] + ss[3];
    q = qq[0] + qq[1] + qq[2] + qq[3];
    float mu   = s * (1.f / NBATCH);
    float var  = fmaxf(q * (1.f / NBATCH) - mu * mu, 0.f);
    float rstd = rsqrtf(var + 1e-3f);
    float a = gamma[c] * rstd;
    sc[c] = a;
    sh[c] = beta[c] - mu * a;
  }
}

// ---------- in-place BN+ReLU on a 256-wide f16 slice of act ----------
__global__ __launch_bounds__(256) void k_bnrelu(half_t* __restrict__ p,
                                                const float* __restrict__ sc,
                                                const float* __restrict__ sh) {
  size_t i = (size_t)blockIdx.x * 256 + threadIdx.x;
  int row = (int)(i >> 5), c8 = (int)(i & 31) << 3;
  half_t* a = p + (size_t)row * 640 + c8;
  half8 v = *(const half8*)a;
  half8 o;
#pragma unroll
  for (int j = 0; j < 8; j++)
    o[j] = (half_t)fmaxf(fmaf((float)v[j], sc[c8 + j], sh[c8 + j]), 0.f);
  *(half8*)a = o;
}

// ---------- softmax helpers ----------
template<int L>
__device__ __forceinline__ void seg_rt(float* __restrict__ zr, int S) {
  float v[L];
#pragma unroll
  for (int j = 0; j < L; j++) v[j] = zr[S + j];
  float m0 = -1e30f, m1 = -1e30f, m2 = -1e30f, m3 = -1e30f;
#pragma unroll
  for (int j = 0; j < L; j++) {
    if ((j & 3) == 0) m0 = fmaxf(m0, v[j]);
    else if ((j & 3) == 1) m1 = fmaxf(m1, v[j]);
    else if ((j & 3) == 2) m2 = fmaxf(m2, v[j]);
    else m3 = fmaxf(m3, v[j]);
  }
  const float m = fmaxf(fmaxf(m0, m1), fmaxf(m2, m3));
  float s0 = 0.f, s1 = 0.f, s2 = 0.f, s3 = 0.f;
#pragma unroll
  for (int j = 0; j < L; j++) {
    float e = __expf(v[j] - m);
    v[j] = e;
    if ((j & 3) == 0) s0 += e;
    else if ((j & 3) == 1) s1 += e;
    else if ((j & 3) == 2) s2 += e;
    else s3 += e;
  }
  const float inv = 1.0f / ((s0 + s1) + (s2 + s3));
#pragma unroll
  for (int j = 0; j < L; j++) zr[S + j] = v[j] * inv;
}

template<int L>
__device__ __forceinline__ void seg_pad(float* __restrict__ zr, int S, int Lr) {
  float v[L];
#pragma unroll
  for (int j = 0; j < L; j++) v[j] = (j < Lr) ? zr[S + j] : -1e30f;
  float m = -1e30f;
#pragma unroll
  for (int j = 0; j < L; j++) m = fmaxf(m, v[j]);
  float s = 0.f;
#pragma unroll
  for (int j = 0; j < L; j++) {
    float e = __expf(v[j] - m);
    v[j] = e;
    s += e;
  }
  const float inv = 1.0f / s;
#pragma unroll
  for (int j = 0; j < L; j++)
    if (j < Lr) zr[S + j] = v[j] * inv;
}

template<int S, int L>
__device__ __forceinline__ void seg_split(float* __restrict__ zr, int par) {
  constexpr int H = L / 2;
  const int base = S + par * H;
  float v[H];
#pragma unroll
  for (int j = 0; j < H; j++) v[j] = zr[base + j];
  float m = -1e30f;
#pragma unroll
  for (int j = 0; j < H; j++) m = fmaxf(m, v[j]);
  m = fmaxf(m, __shfl_xor(m, 1, 64));
  float s = 0.f;
#pragma unroll
  for (int j = 0; j < H; j++) {
    float e = __expf(v[j] - m);
    v[j] = e;
    s += e;
  }
  s += __shfl_xor(s, 1, 64);
  const float inv = 1.0f / s;
#pragma unroll
  for (int j = 0; j < H; j++) zr[base + j] = v[j] * inv;
}

template<int H>
__device__ __forceinline__ void seg_quad(float* __restrict__ zr, int base, int n) {
  float v[H];
#pragma unroll
  for (int j = 0; j < H; j++) v[j] = (j < n) ? zr[base + j] : -1e30f;
  float m = -1e30f;
#pragma unroll
  for (int j = 0; j < H; j++) m = fmaxf(m, v[j]);
  m = fmaxf(m, __shfl_xor(m, 1, 64));
  m = fmaxf(m, __shfl_xor(m, 2, 64));
  float s = 0.f;
#pragma unroll
  for (int j = 0; j < H; j++) {
    float e = __expf(v[j] - m);
    v[j] = e;
    s += e;
  }
  s += __shfl_xor(s, 1, 64);
  s += __shfl_xor(s, 2, 64);
  const float inv = 1.0f / s;
#pragma unroll
  for (int j = 0; j < H; j++)
    if (j < n) zr[base + j] = v[j] * inv;
}

__device__ __forceinline__ bool is_alpha(int c) {
  const unsigned long long AM0 =
      (1ull << 0) | (1ull << 11) | (1ull << 20) | (1ull << 31) | (1ull << 37) |
      (1ull << 48) | (1ull << 59);
  const unsigned long long AM1 = (1ull << 3) | (1ull << 14) | (1ull << 25);  // 67,78,89
  if (c >= 90) return false;
  return (((c < 64) ? (AM0 >> c) : (AM1 >> (c - 64))) & 1ull) != 0ull;
}

// ---------- in-place gumbel-softmax: 32 rows/block ----------
__global__ __launch_bounds__(512, 2) void k_softmax(const float* __restrict__ g,
                                                    float* __restrict__ out) {
  __shared__ float zb[32][373];
  const int tid = threadIdx.x;
  const size_t gbase = (size_t)blockIdx.x * 32 * 366;
  for (int i2 = tid; i2 < 32 * 183; i2 += 512) {
    int e0 = i2 * 2;
    int r = e0 / 366;
    int c = e0 - r * 366;
    float2 lg = *(const float2*)(out + gbase + e0);
    float2 gg = *(const float2*)(g + gbase + e0);
    zb[r][c]     = is_alpha(c)     ? tanhf(lg.x) : (lg.x + gg.x) * 5.0f;
    zb[r][c + 1] = is_alpha(c + 1) ? tanhf(lg.y) : (lg.y + gg.y) * 5.0f;
  }
  __syncthreads();
  {
    const int lane = tid & 63;
    const int w    = tid >> 6;
    const int par  = lane & 1;
    if (w < 4) {
      const int quad = lane & 3;
      float* zr = &zb[(w & 1) * 16 + (lane >> 2)][0];
      if (w < 2) {
        seg_quad<25>(zr, 184 + quad * 25, 25);                       // seg(184,100)
      } else {
        seg_quad<13>(zr, 120 + quad * 13 - (quad >> 1) * (quad & 1), 13 - (quad >> 1));
        seg_rt<10>(zr, par ? 68 : 1);
      }
    } else {
      float* zr = &zb[lane >> 1][0];
      switch (w) {
        case 4: seg_split<314, 30>(zr, par);
                seg_rt<7>(zr, par ? 359 : 60);
                seg_rt<2>(zr, par ? 174 : 100);
                seg_rt<2>(zr, par ? 312 : 290); break;
        case 5: seg_rt<10>(zr, par ? 90 : 38);
                seg_rt<10>(zr, par ? 107 : 49);
                seg_pad<2>(zr, par ? 357 : 0, par ? 2 : 0); break;
        case 6: seg_pad<12>(zr, par ? 348 : 295, par ? 9 : 12);
                seg_pad<6>(zr, par ? 284 : 32, par ? 6 : 5);
                seg_rt<5>(zr, par ? 307 : 102); break;
        default: seg_rt<10>(zr, par ? 79 : 21);
                 seg_rt<8>(zr, par ? 176 : 12);
                 seg_rt<4>(zr, par ? 344 : 170);
                 seg_rt<3>(zr, par ? 292 : 117); break;
      }
    }
  }
  __syncthreads();
  for (int i2 = tid; i2 < 32 * 183; i2 += 512) {
    int e0 = i2 * 2;
    int r = e0 / 366;
    int c = e0 - r * 366;
    float2 o;
    o.x = zb[r][c];
    o.y = zb[r][c + 1];
    *(float2*)(out + gbase + e0) = o;
  }
}

extern "C" void kernel_launch(void* const* d_in, const int* in_sizes, int n_in,
                              void* d_out, int out_size, void* d_ws, size_t ws_size,
                              hipStream_t stream) {
  const float* z      = (const float*)d_in[0];
  const float* g      = (const float*)d_in[1];
  const float* W1     = (const float*)d_in[2];
  const float* b1     = (const float*)d_in[3];
  const float* gamma1 = (const float*)d_in[4];
  const float* beta1  = (const float*)d_in[5];
  const float* W2     = (const float*)d_in[6];
  const float* b2     = (const float*)d_in[7];
  const float* gamma2 = (const float*)d_in[8];
  const float* beta2  = (const float*)d_in[9];
  const float* Wout   = (const float*)d_in[10];
  const float* bout   = (const float*)d_in[11];
  float* out = (float*)d_out;
  char* ws = (char*)d_ws;

  size_t off = 0;
  half_t* act = (half_t*)(ws + off); off += (size_t)NBATCH * 640 * 2;  // [B][p2|p1|z]
  half_t* W1t = (half_t*)(ws + off); off += (size_t)256 * 128 * 2;
  half_t* W2t = (half_t*)(ws + off); off += (size_t)256 * 384 * 2;
  half_t* Wot = (half_t*)(ws + off); off += (size_t)384 * 640 * 2;
  float*  ps  = (float*)(ws + off);  off += (size_t)256 * 1024 * 4;
  float*  pq  = (float*)(ws + off);  off += (size_t)256 * 1024 * 4;
  float*  sc1 = (float*)(ws + off);  off += 256 * 4;
  float*  sh1 = (float*)(ws + off);  off += 256 * 4;
  float*  sc2 = (float*)(ws + off);  off += 256 * 4;
  float*  sh2 = (float*)(ws + off);  off += 256 * 4;
  (void)ws_size; (void)in_sizes; (void)n_in; (void)out_size;

  // prep: z into act cols 512..639, transposed f16 weights
  k_cvtz<<<4096, 256, 0, stream>>>(z, act + 512);
  k_transpose<<<(256 * 128 + 255) / 256, 256, 0, stream>>>(W1, W1t, 128, 256, 256 * 128);
  k_transpose<<<(256 * 384 + 255) / 256, 256, 0, stream>>>(W2, W2t, 384, 256, 256 * 384);
  k_transpose<<<(384 * 640 + 255) / 256, 256, 0, stream>>>(Wout, Wot, 640, 366, 384 * 640);

  // layer 1: h1(f16, act cols 256..511) = z @ W1 + b1, fused stats
  k_gemm<true, true><<<dim3(512, 2), 256, 0, stream>>>(
      act + 512, 640, 128, W1t, b1, act + 256, nullptr, 640, 256, ps, pq);
  k_bnfinal<<<256, 256, 0, stream>>>(ps, pq, gamma1, beta1, sc1, sh1);
  k_bnrelu<<<8192, 256, 0, stream>>>(act + 256, sc1, sh1);

  // layer 2: h2(f16, act cols 0..255) = [p1|z] @ W2 + b2, fused stats
  k_gemm<true, true><<<dim3(512, 2), 256, 0, stream>>>(
      act + 256, 640, 384, W2t, b2, act + 0, nullptr, 640, 256, ps, pq);
  k_bnfinal<<<256, 256, 0, stream>>>(ps, pq, gamma2, beta2, sc2, sh2);
  k_bnrelu<<<8192, 256, 0, stream>>>(act + 0, sc2, sh2);

  // output layer: logits(f32, dense) = [p2|p1|z] @ Wout + bout -> d_out
  k_gemm<false, false><<<dim3(512, 3), 256, 0, stream>>>(
      act, 640, 640, Wot, bout, nullptr, out, 366, 366, nullptr, nullptr);

  // in-place ragged gumbel-softmax + tanh
  k_softmax<<<NBATCH / 32, 512, 0, stream>>>(g, out);
}